// Round 1
// baseline (5681.970 us; speedup 1.0000x reference)
//
#include <hip/hip_runtime.h>
#include <cstdint>
#include <cstddef>

#define T_TOK 2048
#define HIDN  2048
#define NHEAD 16
#define QLRr  1536
#define KVLRr 512
#define DNn   128
#define DRr   64
#define DVv   128
#define QKDd  192
#define INHh  16
#define IHDd  128
#define ITOPKk 512
#define NEXP  8
#define EKk   4
#define MIi   512
#define SHMI  1024
#define EPSF  1e-6f
#define NEGINF (-3.402823466e38f)

// ---------------- helpers ----------------
__device__ __forceinline__ float warp_sum(float v){
#pragma unroll
  for (int off=32; off>0; off>>=1) v += __shfl_down(v, off, 64);
  return v;
}
__device__ __forceinline__ float warp_max(float v){
#pragma unroll
  for (int off=32; off>0; off>>=1) v = fmaxf(v, __shfl_down(v, off, 64));
  return v;
}
__device__ __forceinline__ unsigned mapf(float f){
  unsigned b = __float_as_uint(f);
  if ((b<<1)==0u) b = 0u;                 // canonicalize -0 -> +0 (jax compares equal)
  return (b & 0x80000000u) ? ~b : (b | 0x80000000u);
}

// ---------------- rope tables ----------------
__global__ void rope_table_kernel(const int* __restrict__ pos,
                                  float* __restrict__ ct, float* __restrict__ st){
  int t = blockIdx.x, j = threadIdx.x;          // blockDim 32
  float inv = powf(10000.0f, -(float)j * (1.0f/32.0f));
  float f = (float)pos[t] * inv;
  ct[t*32+j] = cosf(f);
  st[t*32+j] = sinf(f);
}

// ---------------- rmsnorm (generic row) ----------------
__global__ __launch_bounds__(256) void rmsnorm_kernel(
    const float* __restrict__ x, int xstride, int xoff,
    const float* __restrict__ w, float* __restrict__ out, int ostride, int D){
  int t = blockIdx.x, tid = threadIdx.x;
  const float* xp = x + (size_t)t*xstride + xoff;
  const float4* x4 = (const float4*)xp;
  int D4 = D >> 2;
  float ss = 0.f;
  for (int i = tid; i < D4; i += 256){ float4 v = x4[i]; ss += v.x*v.x+v.y*v.y+v.z*v.z+v.w*v.w; }
  __shared__ float red[4];
  float s = warp_sum(ss);
  int lane = tid & 63, wid = tid >> 6;
  if (lane==0) red[wid] = s;
  __syncthreads();
  if (tid==0) red[0] = red[0]+red[1]+red[2]+red[3];
  __syncthreads();
  float sc = rsqrtf(red[0]/(float)D + EPSF);
  const float4* w4 = (const float4*)w;
  float4* o4 = (float4*)(out + (size_t)t*ostride);
  for (int i = tid; i < D4; i += 256){
    float4 v = x4[i], ww = w4[i];
    float4 r; r.x=v.x*sc*ww.x; r.y=v.y*sc*ww.y; r.z=v.z*sc*ww.z; r.w=v.w*sc*ww.w;
    o4[i] = r;
  }
}

// ---------------- k_pe rope ----------------
__global__ void rope_kpe_kernel(const float* __restrict__ qkv,
                                const float* __restrict__ ct, const float* __restrict__ st,
                                float* __restrict__ kpe){
  int t = blockIdx.x, j = threadIdx.x;          // blockDim 32
  const float* x = qkv + (size_t)t*2112 + 2048;
  float x1 = x[j], x2 = x[32+j];
  float c = ct[t*32+j], sn = st[t*32+j];
  kpe[t*64+j]    = x1*c - x2*sn;
  kpe[t*64+32+j] = x1*sn + x2*c;
}

// ---------------- idx_k layernorm + rope (in-place [T,128]) ----------------
__global__ __launch_bounds__(128) void ln_rope_idxk_kernel(
    float* __restrict__ xk, const float* __restrict__ w, const float* __restrict__ b,
    const float* __restrict__ ct, const float* __restrict__ st){
  int t = blockIdx.x, tid = threadIdx.x;        // blockDim 128
  float v = xk[(size_t)t*IHDd + tid];
  float s1 = warp_sum(v), s2 = warp_sum(v*v);
  __shared__ float r1[2], r2[2];
  int lane = tid & 63, wid = tid >> 6;
  if (lane==0){ r1[wid]=s1; r2[wid]=s2; }
  __syncthreads();
  float mean = (r1[0]+r1[1]) * (1.f/128.f);
  float var  = (r2[0]+r2[1]) * (1.f/128.f) - mean*mean;
  float y = (v-mean)*rsqrtf(var+EPSF)*w[tid]+b[tid];
  __shared__ float ly[128];
  ly[tid] = y; __syncthreads();
  float o;
  if (tid < 64) o = y;
  else if (tid < 96){ int j = tid-64; o = ly[64+j]*ct[t*32+j] - ly[96+j]*st[t*32+j]; }
  else              { int j = tid-96; o = ly[64+j]*st[t*32+j] + ly[96+j]*ct[t*32+j]; }
  xk[(size_t)t*IHDd + tid] = o;
}

// ---------------- rope over q ([T,16,192], dims 128..191) ----------------
__global__ __launch_bounds__(256) void rope_q_kernel(float* __restrict__ q,
                                  const float* __restrict__ ct, const float* __restrict__ st){
  int t = blockIdx.x, tid = threadIdx.x;
  __shared__ float c[32], s[32];
  if (tid < 32){ c[tid]=ct[t*32+tid]; s[tid]=st[t*32+tid]; }
  __syncthreads();
  for (int idx = tid; idx < NHEAD*32; idx += 256){
    int hh = idx >> 5, j = idx & 31;
    float* base = q + (size_t)t*(NHEAD*QKDd) + hh*QKDd;
    float x1 = base[DNn+j], x2 = base[DNn+32+j];
    base[DNn+j]    = x1*c[j] - x2*s[j];
    base[DNn+32+j] = x1*s[j] + x2*c[j];
  }
}

// ---------------- rope over idx_q ([T,16,128], dims 64..127) ----------------
__global__ __launch_bounds__(256) void rope_idxq_kernel(float* __restrict__ q,
                                  const float* __restrict__ ct, const float* __restrict__ st){
  int t = blockIdx.x, tid = threadIdx.x;
  __shared__ float c[32], s[32];
  if (tid < 32){ c[tid]=ct[t*32+tid]; s[tid]=st[t*32+tid]; }
  __syncthreads();
  for (int idx = tid; idx < INHh*32; idx += 256){
    int hh = idx >> 5, j = idx & 31;
    float* base = q + (size_t)t*(INHh*IHDd) + hh*IHDd;
    float x1 = base[64+j], x2 = base[96+j];
    base[64+j] = x1*c[j] - x2*s[j];
    base[96+j] = x1*s[j] + x2*c[j];
  }
}

// ---------------- generic fp32 GEMM: C = alpha*A*B (+ addsrc) ----------------
__global__ __launch_bounds__(256) void gemm_f32(
    const float* __restrict__ A, int lda,
    const float* __restrict__ B, int ldb,
    float* __restrict__ C, int ldc,
    const float* __restrict__ addsrc, int ldadd,
    int M, int N, int K, float alpha){
  __shared__ float As[16][68];
  __shared__ float Bs[16][68];
  int tid = threadIdx.x;
  int tx = tid & 15, ty = tid >> 4;
  int m0 = blockIdx.y*64, n0 = blockIdx.x*64;
  float acc[4][4] = {};
  for (int k0 = 0; k0 < K; k0 += 16){
#pragma unroll
    for (int i = 0; i < 4; i++){
      int lin = tid + i*256; int r = lin >> 4, c = lin & 15;
      int m = m0 + r;
      As[c][r] = (m < M) ? A[(size_t)m*lda + k0 + c] : 0.f;
    }
#pragma unroll
    for (int i = 0; i < 4; i++){
      int lin = tid + i*256; int kk = lin >> 6, c = lin & 63;
      int n = n0 + c;
      Bs[kk][c] = (n < N) ? B[(size_t)(k0+kk)*ldb + n] : 0.f;
    }
    __syncthreads();
#pragma unroll
    for (int kk = 0; kk < 16; kk++){
      float4 av = *(const float4*)&As[kk][ty*4];
      float4 bv = *(const float4*)&Bs[kk][tx*4];
      float a[4] = {av.x, av.y, av.z, av.w};
      float b[4] = {bv.x, bv.y, bv.z, bv.w};
#pragma unroll
      for (int i = 0; i < 4; i++)
#pragma unroll
        for (int j = 0; j < 4; j++) acc[i][j] += a[i]*b[j];
    }
    __syncthreads();
  }
#pragma unroll
  for (int i = 0; i < 4; i++){
    int m = m0 + ty*4 + i;
    if (m >= M) continue;
#pragma unroll
    for (int j = 0; j < 4; j++){
      int n = n0 + tx*4 + j;
      if (n >= N) continue;
      float v = acc[i][j]*alpha;
      if (addsrc) v += addsrc[(size_t)m*ldadd + n];
      C[(size_t)m*ldc + n] = v;
    }
  }
}

// ---------------- indexer scores (causal tiles only) ----------------
__global__ __launch_bounds__(256) void iscores_kernel(
    const float* __restrict__ idx_q,   // [T,16,128]
    const float* __restrict__ idx_k,   // [T,128]
    const float* __restrict__ idx_w,   // [T,16]
    float* __restrict__ sc){           // [T,T]
  int sb = blockIdx.x, tb = blockIdx.y;
  if (sb > tb) return;
  int t0 = tb*64, s0 = sb*64;
  __shared__ float As[32][68];
  __shared__ float Bs[32][68];
  __shared__ float Ws[64][17];
  int tid = threadIdx.x, tx = tid & 15, ty = tid >> 4;
  for (int i = tid; i < 1024; i += 256){ int r = i >> 4, hh = i & 15; Ws[r][hh] = idx_w[(size_t)(t0+r)*16 + hh]; }
  float sco[4][4] = {};
  for (int h = 0; h < 16; h++){
    float acc[4][4] = {};
    for (int k0 = 0; k0 < 128; k0 += 32){
#pragma unroll
      for (int i = 0; i < 8; i++){
        int lin = tid + i*256; int r = lin >> 5, c = lin & 31;
        As[c][r] = idx_q[(size_t)(t0+r)*2048 + h*128 + k0 + c];
      }
#pragma unroll
      for (int i = 0; i < 8; i++){
        int lin = tid + i*256; int r = lin >> 5, c = lin & 31;
        Bs[c][r] = idx_k[(size_t)(s0+r)*128 + k0 + c];
      }
      __syncthreads();
#pragma unroll
      for (int kk = 0; kk < 32; kk++){
        float4 av = *(const float4*)&As[kk][ty*4];
        float4 bv = *(const float4*)&Bs[kk][tx*4];
        float a[4] = {av.x, av.y, av.z, av.w};
        float b[4] = {bv.x, bv.y, bv.z, bv.w};
#pragma unroll
        for (int i = 0; i < 4; i++)
#pragma unroll
          for (int j = 0; j < 4; j++) acc[i][j] += a[i]*b[j];
      }
      __syncthreads();
    }
#pragma unroll
    for (int i = 0; i < 4; i++){
      float wv = Ws[ty*4+i][h];
#pragma unroll
      for (int j = 0; j < 4; j++) sco[i][j] += wv * fmaxf(acc[i][j], 0.f);
    }
  }
#pragma unroll
  for (int i = 0; i < 4; i++){
    int tg = t0 + ty*4 + i;
#pragma unroll
    for (int j = 0; j < 4; j++){
      int sg = s0 + tx*4 + j;
      sc[(size_t)tg*2048 + sg] = (sg <= tg) ? sco[i][j] : NEGINF;
    }
  }
}

// ---------------- top-k (k=512) per row, stable ties (lower index first) --------
__global__ __launch_bounds__(256) void topk_kernel(
    const float* __restrict__ scores, int* __restrict__ list, int* __restrict__ cnt){
  int t = blockIdx.x, tid = threadIdx.x;
  if (t < ITOPKk){
    for (int i = tid; i <= t; i += 256) list[(size_t)t*ITOPKk + i] = i;
    if (tid==0) cnt[t] = t+1;
    return;
  }
  int n = t+1;
  const float* row = scores + (size_t)t*2048;
  __shared__ unsigned hist[256];
  __shared__ unsigned sh_prefix, sh_krem;
  __shared__ int scan[256];
  __shared__ int sh_base_sel, sh_base_eq;
  if (tid==0){ sh_prefix = 0u; sh_krem = ITOPKk; }
  __syncthreads();
  for (int level = 3; level >= 0; level--){
    int shift = level*8;
    hist[tid] = 0u; __syncthreads();
    unsigned pfx = sh_prefix;
    for (int s = tid; s < n; s += 256){
      unsigned u = mapf(row[s]);
      bool ok = (level==3) || ((u >> (shift+8)) == pfx);
      if (ok) atomicAdd(&hist[(u >> shift) & 255u], 1u);
    }
    __syncthreads();
    if (tid==0){
      unsigned krem = sh_krem, c = 0u; int bsel = 0;
      for (int b = 255; b >= 0; b--){
        if (c + hist[b] >= krem){ bsel = b; break; }
        c += hist[b];
      }
      sh_prefix = (pfx << 8) | (unsigned)bsel;
      sh_krem = krem - c;
    }
    __syncthreads();
  }
  unsigned uth = sh_prefix; int R = (int)sh_krem;
  if (tid==0){ sh_base_sel = 0; sh_base_eq = 0; }
  __syncthreads();
  for (int c0 = 0; c0 < n; c0 += 256){
    int s = c0 + tid;
    unsigned u = (s < n) ? mapf(row[s]) : 0u;
    int gt = (s < n) && (u > uth);
    int eq = (s < n) && (u == uth);
    scan[tid] = (eq << 16) | gt; __syncthreads();
    for (int off = 1; off < 256; off <<= 1){
      int v = (tid >= off) ? scan[tid-off] : 0; __syncthreads();
      scan[tid] += v; __syncthreads();
    }
    int incl = scan[tid];
    int gt_incl = incl & 0xffff, eq_incl = incl >> 16;
    int gt_excl = gt_incl - gt, eq_excl = eq_incl - eq;
    int tot = scan[255]; int gt_tot = tot & 0xffff, eq_tot = tot >> 16;
    int base_sel = sh_base_sel, base_eq = sh_base_eq;
    int rtake = R - base_eq; if (rtake < 0) rtake = 0;
    bool selected = gt || (eq && eq_excl < rtake);
    int pos = base_sel + gt_excl + min(eq_excl, rtake);
    if (selected) list[(size_t)t*ITOPKk + pos] = s;
    __syncthreads();
    if (tid==0){
      sh_base_sel = base_sel + gt_tot + min(eq_tot, rtake);
      sh_base_eq  = base_eq + eq_tot;
    }
    __syncthreads();
  }
  if (tid==0) cnt[t] = ITOPKk;
}

// ---------------- sparse attention over selected positions ----------------
__global__ __launch_bounds__(256) void attn_kernel(
    const float* __restrict__ q,    // [T,16,192]
    const float* __restrict__ kv,   // [T,16,256]  (k_nope | v)
    const float* __restrict__ kpe,  // [T,64]
    const int* __restrict__ list, const int* __restrict__ cnt,
    float* __restrict__ attn){      // [T,2048]
  int t = blockIdx.x, h = blockIdx.y;
  int tid = threadIdx.x, lane = tid & 63, w = tid >> 6;
  __shared__ float qs[192];
  __shared__ float lg[ITOPKk];
  __shared__ float redm[4], reds[4];
  __shared__ float outp[2][128];
  if (tid < 192) qs[tid] = q[(size_t)t*(NHEAD*QKDd) + h*QKDd + tid];
  int n = cnt[t];
  __syncthreads();
  const float scale = 0.07216878364870323f;   // 192^-0.5
  for (int i = w; i < n; i += 4){
    int s = list[(size_t)t*ITOPKk + i];
    const float* kp = kv + (size_t)s*4096 + h*256;
    float p = qs[lane]*kp[lane] + qs[64+lane]*kp[64+lane] + qs[128+lane]*kpe[(size_t)s*64+lane];
    p = warp_sum(p);
    if (lane==0) lg[i] = p*scale;
  }
  __syncthreads();
  float mx = NEGINF;
  for (int i = tid; i < n; i += 256) mx = fmaxf(mx, lg[i]);
  mx = warp_max(mx);
  if (lane==0) redm[w] = mx;
  __syncthreads();
  mx = fmaxf(fmaxf(redm[0],redm[1]), fmaxf(redm[2],redm[3]));
  float sum = 0.f;
  for (int i = tid; i < n; i += 256){ float p = expf(lg[i]-mx); lg[i] = p; sum += p; }
  sum = warp_sum(sum);
  if (lane==0) reds[w] = sum;
  __syncthreads();
  float inv = 1.f/(reds[0]+reds[1]+reds[2]+reds[3]);
  int half = tid >> 7, d = tid & 127;
  float acc = 0.f;
  for (int i = half; i < n; i += 2){
    int s = list[(size_t)t*ITOPKk + i];
    acc += lg[i]*kv[(size_t)s*4096 + h*256 + 128 + d];
  }
  outp[half][d] = acc; __syncthreads();
  if (tid < 128) attn[(size_t)t*2048 + h*128 + tid] = (outp[0][tid]+outp[1][tid])*inv;
}

// ---------------- gate: softmax + top4 + expert lists ----------------
__global__ void gate_kernel(const float* __restrict__ glog, float* __restrict__ tw,
                            int* __restrict__ ecnt, int* __restrict__ elist){
  int t = blockIdx.x*256 + threadIdx.x;
  if (t >= T_TOK) return;
  float g[8]; float mx = NEGINF;
  for (int i = 0; i < 8; i++){ g[i] = glog[t*8+i]; mx = fmaxf(mx, g[i]); }
  float s = 0.f;
  for (int i = 0; i < 8; i++){ g[i] = expf(g[i]-mx); s += g[i]; }
  for (int i = 0; i < 8; i++) g[i] /= s;
  bool used[8] = {};
  float tv[4]; int si[4];
  for (int k = 0; k < 4; k++){
    float best = -1.f; int bi = 0;
    for (int i = 0; i < 8; i++) if (!used[i] && g[i] > best){ best = g[i]; bi = i; }
    used[bi] = true; tv[k] = best; si[k] = bi;
  }
  float s4 = tv[0]+tv[1]+tv[2]+tv[3];
  for (int k = 0; k < 4; k++){
    tw[t*4+k] = tv[k]/s4;
    int pos = atomicAdd(&ecnt[si[k]], 1);
    elist[si[k]*2048 + pos] = t*4+k;
  }
}

// ---------------- MoE GEMM1: gathered rows, gate+up, silu ----------------
__global__ __launch_bounds__(256) void moe_gemm1(
    const float* __restrict__ h2,     // [T,2048]
    const float* __restrict__ wgu,    // [8,2048,1024]
    const int* __restrict__ ecnt, const int* __restrict__ elist,
    float* __restrict__ act){         // [T*4, 512] indexed by entry
  int e = blockIdx.z;
  int n0 = blockIdx.x*64;
  int r0 = blockIdx.y*64;
  int count = ecnt[e];
  if (r0 >= count) return;
  __shared__ int rows[64];
  __shared__ float As[16][68], B0[16][68], B1[16][68];
  int tid = threadIdx.x, tx = tid & 15, ty = tid >> 4;
  if (tid < 64) rows[tid] = (r0+tid < count) ? elist[e*2048 + r0 + tid] : -1;
  __syncthreads();
  const float* wb = wgu + (size_t)e*2048*1024;
  float acc0[4][4] = {}, acc1[4][4] = {};
  for (int k0 = 0; k0 < 2048; k0 += 16){
#pragma unroll
    for (int i = 0; i < 4; i++){
      int lin = tid + i*256; int r = lin >> 4, c = lin & 15;
      int ent = rows[r];
      As[c][r] = (ent >= 0) ? h2[(size_t)(ent>>2)*2048 + k0 + c] : 0.f;
    }
#pragma unroll
    for (int i = 0; i < 4; i++){
      int lin = tid + i*256; int kk = lin >> 6, c = lin & 63;
      B0[kk][c] = wb[(size_t)(k0+kk)*1024 + n0 + c];
      B1[kk][c] = wb[(size_t)(k0+kk)*1024 + n0 + c + 512];
    }
    __syncthreads();
#pragma unroll
    for (int kk = 0; kk < 16; kk++){
      float4 av = *(const float4*)&As[kk][ty*4];
      float4 b0 = *(const float4*)&B0[kk][tx*4];
      float4 b1 = *(const float4*)&B1[kk][tx*4];
      float a[4] = {av.x,av.y,av.z,av.w};
      float c0[4] = {b0.x,b0.y,b0.z,b0.w};
      float c1[4] = {b1.x,b1.y,b1.z,b1.w};
#pragma unroll
      for (int i = 0; i < 4; i++)
#pragma unroll
        for (int j = 0; j < 4; j++){ acc0[i][j] += a[i]*c0[j]; acc1[i][j] += a[i]*c1[j]; }
    }
    __syncthreads();
  }
#pragma unroll
  for (int i = 0; i < 4; i++){
    int ent = rows[ty*4+i];
    if (ent < 0) continue;
#pragma unroll
    for (int j = 0; j < 4; j++){
      float gv = acc0[i][j], uv = acc1[i][j];
      act[(size_t)ent*512 + n0 + tx*4 + j] = gv/(1.f+expf(-gv))*uv;
    }
  }
}

// ---------------- MoE GEMM2: act @ w_d, weighted by tw ----------------
__global__ __launch_bounds__(256) void moe_gemm2(
    const float* __restrict__ act,    // [T*4,512]
    const float* __restrict__ wd,     // [8,512,2048]
    const int* __restrict__ ecnt, const int* __restrict__ elist,
    const float* __restrict__ tw,
    float* __restrict__ down){        // [T*4,2048]
  int e = blockIdx.z;
  int n0 = blockIdx.x*64;
  int r0 = blockIdx.y*64;
  int count = ecnt[e];
  if (r0 >= count) return;
  __shared__ int rows[64];
  __shared__ float As[16][68], Bs[16][68];
  int tid = threadIdx.x, tx = tid & 15, ty = tid >> 4;
  if (tid < 64) rows[tid] = (r0+tid < count) ? elist[e*2048 + r0 + tid] : -1;
  __syncthreads();
  const float* wb = wd + (size_t)e*512*2048;
  float acc[4][4] = {};
  for (int k0 = 0; k0 < 512; k0 += 16){
#pragma unroll
    for (int i = 0; i < 4; i++){
      int lin = tid + i*256; int r = lin >> 4, c = lin & 15;
      int ent = rows[r];
      As[c][r] = (ent >= 0) ? act[(size_t)ent*512 + k0 + c] : 0.f;
    }
#pragma unroll
    for (int i = 0; i < 4; i++){
      int lin = tid + i*256; int kk = lin >> 6, c = lin & 63;
      Bs[kk][c] = wb[(size_t)(k0+kk)*2048 + n0 + c];
    }
    __syncthreads();
#pragma unroll
    for (int kk = 0; kk < 16; kk++){
      float4 av = *(const float4*)&As[kk][ty*4];
      float4 bv = *(const float4*)&Bs[kk][tx*4];
      float a[4] = {av.x,av.y,av.z,av.w};
      float b[4] = {bv.x,bv.y,bv.z,bv.w};
#pragma unroll
      for (int i = 0; i < 4; i++)
#pragma unroll
        for (int j = 0; j < 4; j++) acc[i][j] += a[i]*b[j];
    }
    __syncthreads();
  }
#pragma unroll
  for (int i = 0; i < 4; i++){
    int ent = rows[ty*4+i];
    if (ent < 0) continue;
    float wgt = tw[ent];
#pragma unroll
    for (int j = 0; j < 4; j++)
      down[(size_t)ent*2048 + n0 + tx*4 + j] = acc[i][j]*wgt;
  }
}

// ---------------- combine 4 expert slots ----------------
__global__ __launch_bounds__(256) void moe_combine(const float* __restrict__ down,
                                                   float* __restrict__ routed){
  int t = blockIdx.x;
  size_t base = (size_t)t*4*2048;
  for (int d = threadIdx.x; d < 2048; d += 256){
    float s = down[base+d] + down[base+2048+d] + down[base+4096+d] + down[base+6144+d];
    routed[(size_t)t*2048 + d] = s;
  }
}

// ---------------- shared-expert silu ----------------
__global__ __launch_bounds__(256) void silu_kernel(const float* __restrict__ sgu,
                                                   float* __restrict__ shact){
  int t = blockIdx.x;
  for (int j = threadIdx.x; j < SHMI; j += 256){
    float g = sgu[(size_t)t*2*SHMI + j], u = sgu[(size_t)t*2*SHMI + SHMI + j];
    shact[(size_t)t*SHMI + j] = g/(1.f+expf(-g))*u;
  }
}

// ---------------- host ----------------
static void launch_gemm(const float* A, int lda, const float* B, int ldb,
                        float* C, int ldc, const float* addsrc, int ldadd,
                        int M, int N, int K, float alpha, hipStream_t stream){
  dim3 grid((N+63)/64, (M+63)/64);
  gemm_f32<<<grid, 256, 0, stream>>>(A, lda, B, ldb, C, ldc, addsrc, ldadd, M, N, K, alpha);
}

extern "C" void kernel_launch(void* const* d_in, const int* in_sizes, int n_in,
                              void* d_out, int out_size, void* d_ws, size_t ws_size,
                              hipStream_t stream){
  const int*   positions  = (const int*)  d_in[0];
  const float* hidden     = (const float*)d_in[1];
  const float* ln1_w      = (const float*)d_in[2];
  const float* ln2_w      = (const float*)d_in[3];
  const float* w_qkv_a    = (const float*)d_in[4];
  const float* q_a_ln_w   = (const float*)d_in[5];
  const float* kv_a_ln_w  = (const float*)d_in[6];
  const float* w_q_b      = (const float*)d_in[7];
  const float* w_kv_b     = (const float*)d_in[8];
  const float* w_o        = (const float*)d_in[9];
  const float* w_idx_k    = (const float*)d_in[10];
  const float* idx_k_ln_w = (const float*)d_in[11];
  const float* idx_k_ln_b = (const float*)d_in[12];
  const float* w_idx_qb   = (const float*)d_in[13];
  const float* w_idx_w    = (const float*)d_in[14];
  const float* w_gate     = (const float*)d_in[15];
  const float* w_moe_gu   = (const float*)d_in[16];
  const float* w_moe_d    = (const float*)d_in[17];
  const float* w_sh_gu    = (const float*)d_in[18];
  const float* w_sh_d     = (const float*)d_in[19];

  float* out_final = (float*)d_out;                          // [T,HID]
  float* residual  = (float*)d_out + (size_t)T_TOK*HIDN;     // [T,HID]

  float* ws = (float*)d_ws;
  // ---- layout (element offsets, with overlays) ----
  size_t off = 0;
  float* h      = ws + off; off += 4194304;                  // [T,2048] (h, later h2)
  size_t offA = off;                                         // region A (later down_buf)
  float* qkv    = ws + offA;                                 // [T,2112]
  float* qbuf   = qkv + 4325376;                             // [T,16,192]
  float* idx_q  = qbuf + 6291456;                            // [T,16,128]
  float* iscores= idx_q + 4194304;                           // [T,T]
  off = offA + 19005440;
  float* down_buf = ws + offA;                               // [T*4,2048] overlay
  size_t offB = off;                                         // region B (later act_buf)
  float* q_c    = ws + offB;                                 // [T,1536]
  float* kv_c   = q_c + 3145728;                             // [T,512]
  float* act_buf= ws + offB;                                 // [T*4,512] overlay
  off = offB + 4194304;
  float* k_pe   = ws + off; off += 131072;                   // [T,64]
  float* idx_k  = ws + off; off += 262144;                   // [T,128]
  float* idx_w  = ws + off; off += 32768;                    // [T,16]
  float* kv     = ws + off; off += 8388608;                  // [T,16,256]
  float* attn   = ws + off; off += 4194304;                  // [T,2048] (later sgu)
  float* sgu    = attn;                                      // [T,2048] overlay
  float* shact  = ws + off; off += 2097152;                  // [T,1024]
  float* routed = ws + off; off += 4194304;                  // [T,2048]
  float* glog   = ws + off; off += 16384;                    // [T,8]
  float* tw     = ws + off; off += 8192;                     // [T,4]
  float* ctab   = ws + off; off += 65536;                    // [T,32]
  float* stab   = ws + off; off += 65536;                    // [T,32]
  int* list     = (int*)(ws + off);                          // [T,512]
  int* cnt      = list + 1048576;                            // [T]
  int* ecnt     = cnt + 2048;                                // [8]
  int* elist    = ecnt + 8;                                  // [8,2048]
  size_t total_bytes = (off + 1067016) * sizeof(float);
  if (ws_size < total_bytes) return;                         // ws too small: bail cleanly

  rope_table_kernel<<<T_TOK, 32, 0, stream>>>(positions, ctab, stab);
  rmsnorm_kernel<<<T_TOK, 256, 0, stream>>>(hidden, HIDN, 0, ln1_w, h, HIDN, HIDN);
  launch_gemm(h, HIDN, w_qkv_a, 2112, qkv, 2112, nullptr, 0, T_TOK, 2112, HIDN, 1.f, stream);
  rmsnorm_kernel<<<T_TOK, 256, 0, stream>>>(qkv, 2112, 0,    q_a_ln_w,  q_c,  QLRr,  QLRr);
  rmsnorm_kernel<<<T_TOK, 256, 0, stream>>>(qkv, 2112, QLRr, kv_a_ln_w, kv_c, KVLRr, KVLRr);
  rope_kpe_kernel<<<T_TOK, 32, 0, stream>>>(qkv, ctab, stab, k_pe);
  launch_gemm(h, HIDN, w_idx_k, IHDd, idx_k, IHDd, nullptr, 0, T_TOK, IHDd, HIDN, 1.f, stream);
  ln_rope_idxk_kernel<<<T_TOK, 128, 0, stream>>>(idx_k, idx_k_ln_w, idx_k_ln_b, ctab, stab);
  launch_gemm(q_c, QLRr, w_q_b, NHEAD*QKDd, qbuf, NHEAD*QKDd, nullptr, 0, T_TOK, NHEAD*QKDd, QLRr, 1.f, stream);
  rope_q_kernel<<<T_TOK, 256, 0, stream>>>(qbuf, ctab, stab);
  launch_gemm(q_c, QLRr, w_idx_qb, INHh*IHDd, idx_q, INHh*IHDd, nullptr, 0, T_TOK, INHh*IHDd, QLRr, 1.f, stream);
  rope_idxq_kernel<<<T_TOK, 256, 0, stream>>>(idx_q, ctab, stab);
  launch_gemm(h, HIDN, w_idx_w, INHh, idx_w, INHh, nullptr, 0, T_TOK, INHh, HIDN, 0.02209708691207961f, stream);
  iscores_kernel<<<dim3(32,32), 256, 0, stream>>>(idx_q, idx_k, idx_w, iscores);
  topk_kernel<<<T_TOK, 256, 0, stream>>>(iscores, list, cnt);
  launch_gemm(kv_c, KVLRr, w_kv_b, NHEAD*(DNn+DVv), kv, NHEAD*(DNn+DVv), nullptr, 0, T_TOK, NHEAD*(DNn+DVv), KVLRr, 1.f, stream);
  attn_kernel<<<dim3(T_TOK, NHEAD), 256, 0, stream>>>(qbuf, kv, k_pe, list, cnt, attn);
  launch_gemm(attn, NHEAD*DVv, w_o, HIDN, residual, HIDN, hidden, HIDN, T_TOK, HIDN, NHEAD*DVv, 1.f, stream);
  rmsnorm_kernel<<<T_TOK, 256, 0, stream>>>(residual, HIDN, 0, ln2_w, h, HIDN, HIDN);
  launch_gemm(h, HIDN, w_gate, NEXP, glog, NEXP, nullptr, 0, T_TOK, NEXP, HIDN, 1.f, stream);
  hipMemsetAsync(ecnt, 0, NEXP*sizeof(int), stream);
  gate_kernel<<<8, 256, 0, stream>>>(glog, tw, ecnt, elist);
  moe_gemm1<<<dim3(8, 32, NEXP), 256, 0, stream>>>(h, w_moe_gu, ecnt, elist, act_buf);
  moe_gemm2<<<dim3(32, 32, NEXP), 256, 0, stream>>>(act_buf, w_moe_d, ecnt, elist, tw, down_buf);
  moe_combine<<<T_TOK, 256, 0, stream>>>(down_buf, routed);
  launch_gemm(h, HIDN, w_sh_gu, 2*SHMI, sgu, 2*SHMI, nullptr, 0, T_TOK, 2*SHMI, HIDN, 1.f, stream);
  silu_kernel<<<T_TOK, 256, 0, stream>>>(sgu, shact);
  launch_gemm(shact, SHMI, w_sh_d, HIDN, out_final, HIDN, routed, HIDN, T_TOK, HIDN, SHMI, 1.f, stream);
  (void)in_sizes; (void)n_in; (void)out_size;
}

// Round 2
// 5603.468 us; speedup vs baseline: 1.0140x; 1.0140x over previous
//
#include <hip/hip_runtime.h>
#include <cstdint>
#include <cstddef>

#define T_TOK 2048
#define HIDN  2048
#define NHEAD 16
#define QLRr  1536
#define KVLRr 512
#define DNn   128
#define DRr   64
#define DVv   128
#define QKDd  192
#define INHh  16
#define IHDd  128
#define ITOPKk 512
#define NEXP  8
#define EKk   4
#define MIi   512
#define SHMI  1024
#define EPSF  1e-6f
#define NEGINF (-3.402823466e38f)

// ---------------- helpers ----------------
__device__ __forceinline__ float warp_sum(float v){
#pragma unroll
  for (int off=32; off>0; off>>=1) v += __shfl_down(v, off, 64);
  return v;
}
__device__ __forceinline__ float warp_max(float v){
#pragma unroll
  for (int off=32; off>0; off>>=1) v = fmaxf(v, __shfl_down(v, off, 64));
  return v;
}
__device__ __forceinline__ unsigned mapf(float f){
  unsigned b = __float_as_uint(f);
  if ((b<<1)==0u) b = 0u;                 // canonicalize -0 -> +0
  return (b & 0x80000000u) ? ~b : (b | 0x80000000u);
}

// ---------------- rope tables ----------------
__global__ void rope_table_kernel(const int* __restrict__ pos,
                                  float* __restrict__ ct, float* __restrict__ st){
  int t = blockIdx.x, j = threadIdx.x;          // blockDim 32
  float inv = powf(10000.0f, -(float)j * (1.0f/32.0f));
  float f = (float)pos[t] * inv;
  ct[t*32+j] = cosf(f);
  st[t*32+j] = sinf(f);
}

// ---------------- rmsnorm (generic row) ----------------
__global__ __launch_bounds__(256) void rmsnorm_kernel(
    const float* __restrict__ x, int xstride, int xoff,
    const float* __restrict__ w, float* __restrict__ out, int ostride, int D){
  int t = blockIdx.x, tid = threadIdx.x;
  const float* xp = x + (size_t)t*xstride + xoff;
  const float4* x4 = (const float4*)xp;
  int D4 = D >> 2;
  float ss = 0.f;
  for (int i = tid; i < D4; i += 256){ float4 v = x4[i]; ss += v.x*v.x+v.y*v.y+v.z*v.z+v.w*v.w; }
  __shared__ float red[4];
  float s = warp_sum(ss);
  int lane = tid & 63, wid = tid >> 6;
  if (lane==0) red[wid] = s;
  __syncthreads();
  if (tid==0) red[0] = red[0]+red[1]+red[2]+red[3];
  __syncthreads();
  float sc = rsqrtf(red[0]/(float)D + EPSF);
  const float4* w4 = (const float4*)w;
  float4* o4 = (float4*)(out + (size_t)t*ostride);
  for (int i = tid; i < D4; i += 256){
    float4 v = x4[i], ww = w4[i];
    float4 r; r.x=v.x*sc*ww.x; r.y=v.y*sc*ww.y; r.z=v.z*sc*ww.z; r.w=v.w*sc*ww.w;
    o4[i] = r;
  }
}

// ---------------- k_pe rope ----------------
__global__ void rope_kpe_kernel(const float* __restrict__ qkv,
                                const float* __restrict__ ct, const float* __restrict__ st,
                                float* __restrict__ kpe){
  int t = blockIdx.x, j = threadIdx.x;          // blockDim 32
  const float* x = qkv + (size_t)t*2112 + 2048;
  float x1 = x[j], x2 = x[32+j];
  float c = ct[t*32+j], sn = st[t*32+j];
  kpe[t*64+j]    = x1*c - x2*sn;
  kpe[t*64+32+j] = x1*sn + x2*c;
}

// ---------------- idx_k layernorm + rope (in-place [T,128]) ----------------
__global__ __launch_bounds__(128) void ln_rope_idxk_kernel(
    float* __restrict__ xk, const float* __restrict__ w, const float* __restrict__ b,
    const float* __restrict__ ct, const float* __restrict__ st){
  int t = blockIdx.x, tid = threadIdx.x;        // blockDim 128
  float v = xk[(size_t)t*IHDd + tid];
  float s1 = warp_sum(v), s2 = warp_sum(v*v);
  __shared__ float r1[2], r2[2];
  int lane = tid & 63, wid = tid >> 6;
  if (lane==0){ r1[wid]=s1; r2[wid]=s2; }
  __syncthreads();
  float mean = (r1[0]+r1[1]) * (1.f/128.f);
  float var  = (r2[0]+r2[1]) * (1.f/128.f) - mean*mean;
  float y = (v-mean)*rsqrtf(var+EPSF)*w[tid]+b[tid];
  __shared__ float ly[128];
  ly[tid] = y; __syncthreads();
  float o;
  if (tid < 64) o = y;
  else if (tid < 96){ int j = tid-64; o = ly[64+j]*ct[t*32+j] - ly[96+j]*st[t*32+j]; }
  else              { int j = tid-96; o = ly[64+j]*st[t*32+j] + ly[96+j]*ct[t*32+j]; }
  xk[(size_t)t*IHDd + tid] = o;
}

// ---------------- rope over q ([T,16,192], dims 128..191) ----------------
__global__ __launch_bounds__(256) void rope_q_kernel(float* __restrict__ q,
                                  const float* __restrict__ ct, const float* __restrict__ st){
  int t = blockIdx.x, tid = threadIdx.x;
  __shared__ float c[32], s[32];
  if (tid < 32){ c[tid]=ct[t*32+tid]; s[tid]=st[t*32+tid]; }
  __syncthreads();
  for (int idx = tid; idx < NHEAD*32; idx += 256){
    int hh = idx >> 5, j = idx & 31;
    float* base = q + (size_t)t*(NHEAD*QKDd) + hh*QKDd;
    float x1 = base[DNn+j], x2 = base[DNn+32+j];
    base[DNn+j]    = x1*c[j] - x2*s[j];
    base[DNn+32+j] = x1*s[j] + x2*c[j];
  }
}

// ---------------- rope over idx_q ([T,16,128], dims 64..127) ----------------
__global__ __launch_bounds__(256) void rope_idxq_kernel(float* __restrict__ q,
                                  const float* __restrict__ ct, const float* __restrict__ st){
  int t = blockIdx.x, tid = threadIdx.x;
  __shared__ float c[32], s[32];
  if (tid < 32){ c[tid]=ct[t*32+tid]; s[tid]=st[t*32+tid]; }
  __syncthreads();
  for (int idx = tid; idx < INHh*32; idx += 256){
    int hh = idx >> 5, j = idx & 31;
    float* base = q + (size_t)t*(INHh*IHDd) + hh*IHDd;
    float x1 = base[64+j], x2 = base[96+j];
    base[64+j] = x1*c[j] - x2*s[j];
    base[96+j] = x1*s[j] + x2*c[j];
  }
}

// ---------------- fp32 GEMM, 64x64 tile (small N) ----------------
__global__ __launch_bounds__(256) void gemm_f32(
    const float* __restrict__ A, int lda,
    const float* __restrict__ B, int ldb,
    float* __restrict__ C, int ldc,
    const float* __restrict__ addsrc, int ldadd,
    int M, int N, int K, float alpha){
  __shared__ float As[16][68];
  __shared__ float Bs[16][68];
  int tid = threadIdx.x;
  int tx = tid & 15, ty = tid >> 4;
  int m0 = blockIdx.y*64, n0 = blockIdx.x*64;
  float acc[4][4] = {};
  for (int k0 = 0; k0 < K; k0 += 16){
#pragma unroll
    for (int i = 0; i < 4; i++){
      int lin = tid + i*256; int r = lin >> 4, c = lin & 15;
      int m = m0 + r;
      As[c][r] = (m < M) ? A[(size_t)m*lda + k0 + c] : 0.f;
    }
#pragma unroll
    for (int i = 0; i < 4; i++){
      int lin = tid + i*256; int kk = lin >> 6, c = lin & 63;
      int n = n0 + c;
      Bs[kk][c] = (n < N) ? B[(size_t)(k0+kk)*ldb + n] : 0.f;
    }
    __syncthreads();
#pragma unroll
    for (int kk = 0; kk < 16; kk++){
      float4 av = *(const float4*)&As[kk][ty*4];
      float4 bv = *(const float4*)&Bs[kk][tx*4];
      float a[4] = {av.x, av.y, av.z, av.w};
      float b[4] = {bv.x, bv.y, bv.z, bv.w};
#pragma unroll
      for (int i = 0; i < 4; i++)
#pragma unroll
        for (int j = 0; j < 4; j++) acc[i][j] += a[i]*b[j];
    }
    __syncthreads();
  }
#pragma unroll
  for (int i = 0; i < 4; i++){
    int m = m0 + ty*4 + i;
    if (m >= M) continue;
#pragma unroll
    for (int j = 0; j < 4; j++){
      int n = n0 + tx*4 + j;
      if (n >= N) continue;
      float v = acc[i][j]*alpha;
      if (addsrc) v += addsrc[(size_t)m*ldadd + n];
      C[(size_t)m*ldc + n] = v;
    }
  }
}

// ---------------- fp32 GEMM, 128x128 tile, 8x8 micro ----------------
__device__ __forceinline__ int bswz(int col){ return col + ((col >> 5) << 2); }

__global__ __launch_bounds__(256) void gemm_f32_128(
    const float* __restrict__ A, int lda,
    const float* __restrict__ B, int ldb,
    float* __restrict__ C, int ldc,
    const float* __restrict__ addsrc, int ldadd,
    int M, int N, int K, float alpha){
  __shared__ float As[16][132];
  __shared__ float Bs[16][144];
  int tid = threadIdx.x;
  int tx = tid & 15, ty = tid >> 4;
  int m0 = blockIdx.y*128, n0 = blockIdx.x*128;
  int pc0 = bswz(tx*8);
  float acc[8][8] = {};
  for (int k0 = 0; k0 < K; k0 += 16){
#pragma unroll
    for (int i = 0; i < 2; i++){
      int f = tid + i*256; int r = f >> 2, kq = f & 3;
      float4 v = {0,0,0,0};
      if (m0 + r < M) v = *(const float4*)(A + (size_t)(m0+r)*lda + k0 + kq*4);
      As[kq*4+0][r]=v.x; As[kq*4+1][r]=v.y; As[kq*4+2][r]=v.z; As[kq*4+3][r]=v.w;
    }
#pragma unroll
    for (int i = 0; i < 2; i++){
      int f = tid + i*256; int kk = f >> 5, nq = f & 31;
      int n = n0 + nq*4;
      const float* bp = B + (size_t)(k0+kk)*ldb + n;
      float4 v;
      if (n + 3 < N) v = *(const float4*)bp;
      else { v.x = (n<N)?bp[0]:0.f; v.y = (n+1<N)?bp[1]:0.f; v.z = (n+2<N)?bp[2]:0.f; v.w = (n+3<N)?bp[3]:0.f; }
      *(float4*)&Bs[kk][bswz(nq*4)] = v;
    }
    __syncthreads();
#pragma unroll
    for (int kk = 0; kk < 16; kk++){
      float4 a0 = *(const float4*)&As[kk][ty*8];
      float4 a1 = *(const float4*)&As[kk][ty*8+4];
      float4 b0 = *(const float4*)&Bs[kk][pc0];
      float4 b1 = *(const float4*)&Bs[kk][pc0+4];
      float a[8] = {a0.x,a0.y,a0.z,a0.w,a1.x,a1.y,a1.z,a1.w};
      float b[8] = {b0.x,b0.y,b0.z,b0.w,b1.x,b1.y,b1.z,b1.w};
#pragma unroll
      for (int i = 0; i < 8; i++)
#pragma unroll
        for (int j = 0; j < 8; j++) acc[i][j] += a[i]*b[j];
    }
    __syncthreads();
  }
  bool fullN = (n0 + 128 <= N);
#pragma unroll
  for (int i = 0; i < 8; i++){
    int m = m0 + ty*8 + i;
    if (m >= M) continue;
    if (fullN){
      float* cp = C + (size_t)m*ldc + n0 + tx*8;
      float4 o0, o1;
      o0.x=acc[i][0]*alpha; o0.y=acc[i][1]*alpha; o0.z=acc[i][2]*alpha; o0.w=acc[i][3]*alpha;
      o1.x=acc[i][4]*alpha; o1.y=acc[i][5]*alpha; o1.z=acc[i][6]*alpha; o1.w=acc[i][7]*alpha;
      if (addsrc){
        const float* ap = addsrc + (size_t)m*ldadd + n0 + tx*8;
        float4 s0 = *(const float4*)ap, s1 = *(const float4*)(ap+4);
        o0.x+=s0.x; o0.y+=s0.y; o0.z+=s0.z; o0.w+=s0.w;
        o1.x+=s1.x; o1.y+=s1.y; o1.z+=s1.z; o1.w+=s1.w;
      }
      *(float4*)cp = o0; *(float4*)(cp+4) = o1;
    } else {
#pragma unroll
      for (int j = 0; j < 8; j++){
        int n = n0 + tx*8 + j;
        if (n >= N) continue;
        float v = acc[i][j]*alpha;
        if (addsrc) v += addsrc[(size_t)m*ldadd + n];
        C[(size_t)m*ldc + n] = v;
      }
    }
  }
}

// ---------------- indexer scores (causal tiles only) ----------------
__global__ __launch_bounds__(256) void iscores_kernel(
    const float* __restrict__ idx_q,   // [T,16,128]
    const float* __restrict__ idx_k,   // [T,128]
    const float* __restrict__ idx_w,   // [T,16]
    float* __restrict__ sc){           // [T,T]
  int sb = blockIdx.x, tb = blockIdx.y;
  if (sb > tb) return;
  int t0 = tb*64, s0 = sb*64;
  __shared__ float As[32][68];
  __shared__ float Bs[32][68];
  __shared__ float Ws[64][17];
  int tid = threadIdx.x, tx = tid & 15, ty = tid >> 4;
  for (int i = tid; i < 1024; i += 256){ int r = i >> 4, hh = i & 15; Ws[r][hh] = idx_w[(size_t)(t0+r)*16 + hh]; }
  float sco[4][4] = {};
  for (int h = 0; h < 16; h++){
    float acc[4][4] = {};
    for (int k0 = 0; k0 < 128; k0 += 32){
#pragma unroll
      for (int i = 0; i < 8; i++){
        int lin = tid + i*256; int r = lin >> 5, c = lin & 31;
        As[c][r] = idx_q[(size_t)(t0+r)*2048 + h*128 + k0 + c];
      }
#pragma unroll
      for (int i = 0; i < 8; i++){
        int lin = tid + i*256; int r = lin >> 5, c = lin & 31;
        Bs[c][r] = idx_k[(size_t)(s0+r)*128 + k0 + c];
      }
      __syncthreads();
#pragma unroll
      for (int kk = 0; kk < 32; kk++){
        float4 av = *(const float4*)&As[kk][ty*4];
        float4 bv = *(const float4*)&Bs[kk][tx*4];
        float a[4] = {av.x, av.y, av.z, av.w};
        float b[4] = {bv.x, bv.y, bv.z, bv.w};
#pragma unroll
        for (int i = 0; i < 4; i++)
#pragma unroll
          for (int j = 0; j < 4; j++) acc[i][j] += a[i]*b[j];
      }
      __syncthreads();
    }
#pragma unroll
    for (int i = 0; i < 4; i++){
      float wv = Ws[ty*4+i][h];
#pragma unroll
      for (int j = 0; j < 4; j++) sco[i][j] += wv * fmaxf(acc[i][j], 0.f);
    }
  }
#pragma unroll
  for (int i = 0; i < 4; i++){
    int tg = t0 + ty*4 + i;
#pragma unroll
    for (int j = 0; j < 4; j++){
      int sg = s0 + tx*4 + j;
      sc[(size_t)tg*2048 + sg] = (sg <= tg) ? sco[i][j] : NEGINF;
    }
  }
}

// ---------------- top-k (k=512) per row, stable ties --------
__global__ __launch_bounds__(256) void topk_kernel(
    const float* __restrict__ scores, int* __restrict__ list, int* __restrict__ cnt){
  int t = blockIdx.x, tid = threadIdx.x;
  if (t < ITOPKk){
    for (int i = tid; i <= t; i += 256) list[(size_t)t*ITOPKk + i] = i;
    if (tid==0) cnt[t] = t+1;
    return;
  }
  int n = t+1;
  const float* row = scores + (size_t)t*2048;
  __shared__ unsigned hist[256];
  __shared__ unsigned sh_prefix, sh_krem;
  __shared__ int scan[256];
  __shared__ int sh_base_sel, sh_base_eq;
  if (tid==0){ sh_prefix = 0u; sh_krem = ITOPKk; }
  __syncthreads();
  for (int level = 3; level >= 0; level--){
    int shift = level*8;
    hist[tid] = 0u; __syncthreads();
    unsigned pfx = sh_prefix;
    for (int s = tid; s < n; s += 256){
      unsigned u = mapf(row[s]);
      bool ok = (level==3) || ((u >> (shift+8)) == pfx);
      if (ok) atomicAdd(&hist[(u >> shift) & 255u], 1u);
    }
    __syncthreads();
    if (tid==0){
      unsigned krem = sh_krem, c = 0u; int bsel = 0;
      for (int b = 255; b >= 0; b--){
        if (c + hist[b] >= krem){ bsel = b; break; }
        c += hist[b];
      }
      sh_prefix = (pfx << 8) | (unsigned)bsel;
      sh_krem = krem - c;
    }
    __syncthreads();
  }
  unsigned uth = sh_prefix; int R = (int)sh_krem;
  if (tid==0){ sh_base_sel = 0; sh_base_eq = 0; }
  __syncthreads();
  for (int c0 = 0; c0 < n; c0 += 256){
    int s = c0 + tid;
    unsigned u = (s < n) ? mapf(row[s]) : 0u;
    int gt = (s < n) && (u > uth);
    int eq = (s < n) && (u == uth);
    scan[tid] = (eq << 16) | gt; __syncthreads();
    for (int off = 1; off < 256; off <<= 1){
      int v = (tid >= off) ? scan[tid-off] : 0; __syncthreads();
      scan[tid] += v; __syncthreads();
    }
    int incl = scan[tid];
    int gt_incl = incl & 0xffff, eq_incl = incl >> 16;
    int gt_excl = gt_incl - gt, eq_excl = eq_incl - eq;
    int tot = scan[255]; int gt_tot = tot & 0xffff, eq_tot = tot >> 16;
    int base_sel = sh_base_sel, base_eq = sh_base_eq;
    int rtake = R - base_eq; if (rtake < 0) rtake = 0;
    bool selected = gt || (eq && eq_excl < rtake);
    int pos = base_sel + gt_excl + min(eq_excl, rtake);
    if (selected) list[(size_t)t*ITOPKk + pos] = s;
    __syncthreads();
    if (tid==0){
      sh_base_sel = base_sel + gt_tot + min(eq_tot, rtake);
      sh_base_eq  = base_eq + eq_tot;
    }
    __syncthreads();
  }
  if (tid==0) cnt[t] = ITOPKk;
}

// ---------------- sparse attention: block = (t, 4-head group) ----------------
#define HG 4
__global__ __launch_bounds__(256) void attn_kernel(
    const float* __restrict__ q,    // [T,16,192]
    const float* __restrict__ kv,   // [T,16,256]  (k_nope | v)
    const float* __restrict__ kpe,  // [T,64]
    const int* __restrict__ list, const int* __restrict__ cnt,
    float* __restrict__ attn){      // [T,2048]
  int t = blockIdx.x, h0 = blockIdx.y*HG;
  int tid = threadIdx.x, lane = tid & 63, w = tid >> 6;
  __shared__ int   sl[ITOPKk];
  __shared__ float qs[HG][200];
  __shared__ float lg[ITOPKk];
  __shared__ float redm[4], reds[4];
  __shared__ float4 outp4[8][32];
  int n = cnt[t];
  for (int i = tid; i < n; i += 256) sl[i] = list[(size_t)t*ITOPKk + i];
  for (int i = tid; i < HG*192; i += 256){
    int hh = i/192, d = i - hh*192;
    qs[hh][d] = q[(size_t)t*(NHEAD*QKDd) + (h0+hh)*QKDd + d];
  }
  __syncthreads();
  const float scale = 0.07216878364870323f;   // 192^-0.5
  int quarter = lane >> 4, s16 = lane & 15;
  int slice = tid & 31, sg = tid >> 5;
  for (int hh = 0; hh < HG; hh++){
    int h = h0 + hh;
    // ---- QK: 4 lanes per s ----
    for (int p0 = 0; p0 < n; p0 += 64){
      int i = p0 + w*16 + s16;
      float part = 0.f;
      if (i < n){
        int s = sl[i];
        const float* kp = kv + (size_t)s*4096 + h*256 + quarter*32;
        const float* pp = kpe + (size_t)s*64 + quarter*16;
        const float* qn = &qs[hh][quarter*32];
        const float* qp = &qs[hh][128 + quarter*16];
#pragma unroll
        for (int j = 0; j < 8; j++){
          float4 kvv = *(const float4*)(kp + j*4);
          float4 qv  = *(const float4*)(qn + j*4);
          part += kvv.x*qv.x + kvv.y*qv.y + kvv.z*qv.z + kvv.w*qv.w;
        }
#pragma unroll
        for (int j = 0; j < 4; j++){
          float4 kvv = *(const float4*)(pp + j*4);
          float4 qv  = *(const float4*)(qp + j*4);
          part += kvv.x*qv.x + kvv.y*qv.y + kvv.z*qv.z + kvv.w*qv.w;
        }
      }
      part += __shfl_down(part, 32, 64);
      part += __shfl_down(part, 16, 64);
      if (quarter == 0 && i < n) lg[i] = part*scale;
    }
    __syncthreads();
    // ---- softmax ----
    float mx = NEGINF;
    for (int i = tid; i < n; i += 256) mx = fmaxf(mx, lg[i]);
    mx = warp_max(mx);
    if (lane==0) redm[w] = mx;
    __syncthreads();
    mx = fmaxf(fmaxf(redm[0],redm[1]), fmaxf(redm[2],redm[3]));
    float sum = 0.f;
    for (int i = tid; i < n; i += 256){ float p = expf(lg[i]-mx); lg[i] = p; sum += p; }
    sum = warp_sum(sum);
    if (lane==0) reds[w] = sum;
    __syncthreads();
    float inv = 1.f/(reds[0]+reds[1]+reds[2]+reds[3]);
    // ---- PV: thread owns 4-dim slice, 8 s-groups ----
    float4 acc = {0,0,0,0};
    for (int i = sg; i < n; i += 8){
      float p = lg[i];
      float4 v4 = *((const float4*)(kv + (size_t)sl[i]*4096 + h*256 + 128) + slice);
      acc.x += p*v4.x; acc.y += p*v4.y; acc.z += p*v4.z; acc.w += p*v4.w;
    }
    outp4[sg][slice] = acc;
    __syncthreads();
    if (tid < 32){
      float4 r = outp4[0][tid];
#pragma unroll
      for (int g = 1; g < 8; g++){
        float4 o = outp4[g][tid];
        r.x += o.x; r.y += o.y; r.z += o.z; r.w += o.w;
      }
      r.x *= inv; r.y *= inv; r.z *= inv; r.w *= inv;
      *(float4*)&attn[(size_t)t*2048 + h*128 + tid*4] = r;
    }
    __syncthreads();
  }
}

// ---------------- gate: softmax + top4 + expert lists ----------------
__global__ void gate_kernel(const float* __restrict__ glog, float* __restrict__ tw,
                            int* __restrict__ ecnt, int* __restrict__ elist){
  int t = blockIdx.x*256 + threadIdx.x;
  if (t >= T_TOK) return;
  float g[8]; float mx = NEGINF;
  for (int i = 0; i < 8; i++){ g[i] = glog[t*8+i]; mx = fmaxf(mx, g[i]); }
  float s = 0.f;
  for (int i = 0; i < 8; i++){ g[i] = expf(g[i]-mx); s += g[i]; }
  for (int i = 0; i < 8; i++) g[i] /= s;
  bool used[8] = {};
  float tv[4]; int si[4];
  for (int k = 0; k < 4; k++){
    float best = -1.f; int bi = 0;
    for (int i = 0; i < 8; i++) if (!used[i] && g[i] > best){ best = g[i]; bi = i; }
    used[bi] = true; tv[k] = best; si[k] = bi;
  }
  float s4 = tv[0]+tv[1]+tv[2]+tv[3];
  for (int k = 0; k < 4; k++){
    tw[t*4+k] = tv[k]/s4;
    int pos = atomicAdd(&ecnt[si[k]], 1);
    elist[si[k]*2048 + pos] = t*4+k;
  }
}

// ---------------- MoE GEMM1: gathered rows, gate+up, silu ----------------
__global__ __launch_bounds__(256) void moe_gemm1(
    const float* __restrict__ h2,     // [T,2048]
    const float* __restrict__ wgu,    // [8,2048,1024]
    const int* __restrict__ ecnt, const int* __restrict__ elist,
    float* __restrict__ act){         // [T*4, 512]
  int e = blockIdx.z;
  int n0 = blockIdx.x*64;
  int r0 = blockIdx.y*64;
  int count = ecnt[e];
  if (r0 >= count) return;
  __shared__ int rows[64];
  __shared__ float As[16][68], B0[16][68], B1[16][68];
  int tid = threadIdx.x, tx = tid & 15, ty = tid >> 4;
  if (tid < 64) rows[tid] = (r0+tid < count) ? elist[e*2048 + r0 + tid] : -1;
  __syncthreads();
  const float* wb = wgu + (size_t)e*2048*1024;
  float acc0[4][4] = {}, acc1[4][4] = {};
  for (int k0 = 0; k0 < 2048; k0 += 16){
#pragma unroll
    for (int i = 0; i < 4; i++){
      int lin = tid + i*256; int r = lin >> 4, c = lin & 15;
      int ent = rows[r];
      As[c][r] = (ent >= 0) ? h2[(size_t)(ent>>2)*2048 + k0 + c] : 0.f;
    }
#pragma unroll
    for (int i = 0; i < 4; i++){
      int lin = tid + i*256; int kk = lin >> 6, c = lin & 63;
      B0[kk][c] = wb[(size_t)(k0+kk)*1024 + n0 + c];
      B1[kk][c] = wb[(size_t)(k0+kk)*1024 + n0 + c + 512];
    }
    __syncthreads();
#pragma unroll
    for (int kk = 0; kk < 16; kk++){
      float4 av = *(const float4*)&As[kk][ty*4];
      float4 b0 = *(const float4*)&B0[kk][tx*4];
      float4 b1 = *(const float4*)&B1[kk][tx*4];
      float a[4] = {av.x,av.y,av.z,av.w};
      float c0[4] = {b0.x,b0.y,b0.z,b0.w};
      float c1[4] = {b1.x,b1.y,b1.z,b1.w};
#pragma unroll
      for (int i = 0; i < 4; i++)
#pragma unroll
        for (int j = 0; j < 4; j++){ acc0[i][j] += a[i]*c0[j]; acc1[i][j] += a[i]*c1[j]; }
    }
    __syncthreads();
  }
#pragma unroll
  for (int i = 0; i < 4; i++){
    int ent = rows[ty*4+i];
    if (ent < 0) continue;
#pragma unroll
    for (int j = 0; j < 4; j++){
      float gv = acc0[i][j], uv = acc1[i][j];
      act[(size_t)ent*512 + n0 + tx*4 + j] = gv/(1.f+expf(-gv))*uv;
    }
  }
}

// ---------------- MoE GEMM2: act @ w_d, weighted by tw ----------------
__global__ __launch_bounds__(256) void moe_gemm2(
    const float* __restrict__ act,    // [T*4,512]
    const float* __restrict__ wd,     // [8,512,2048]
    const int* __restrict__ ecnt, const int* __restrict__ elist,
    const float* __restrict__ tw,
    float* __restrict__ down){        // [T*4,2048]
  int e = blockIdx.z;
  int n0 = blockIdx.x*64;
  int r0 = blockIdx.y*64;
  int count = ecnt[e];
  if (r0 >= count) return;
  __shared__ int rows[64];
  __shared__ float As[16][68], Bs[16][68];
  int tid = threadIdx.x, tx = tid & 15, ty = tid >> 4;
  if (tid < 64) rows[tid] = (r0+tid < count) ? elist[e*2048 + r0 + tid] : -1;
  __syncthreads();
  const float* wb = wd + (size_t)e*512*2048;
  float acc[4][4] = {};
  for (int k0 = 0; k0 < 512; k0 += 16){
#pragma unroll
    for (int i = 0; i < 4; i++){
      int lin = tid + i*256; int r = lin >> 4, c = lin & 15;
      int ent = rows[r];
      As[c][r] = (ent >= 0) ? act[(size_t)ent*512 + k0 + c] : 0.f;
    }
#pragma unroll
    for (int i = 0; i < 4; i++){
      int lin = tid + i*256; int kk = lin >> 6, c = lin & 63;
      Bs[kk][c] = wb[(size_t)(k0+kk)*2048 + n0 + c];
    }
    __syncthreads();
#pragma unroll
    for (int kk = 0; kk < 16; kk++){
      float4 av = *(const float4*)&As[kk][ty*4];
      float4 bv = *(const float4*)&Bs[kk][tx*4];
      float a[4] = {av.x,av.y,av.z,av.w};
      float b[4] = {bv.x,bv.y,bv.z,bv.w};
#pragma unroll
      for (int i = 0; i < 4; i++)
#pragma unroll
        for (int j = 0; j < 4; j++) acc[i][j] += a[i]*b[j];
    }
    __syncthreads();
  }
#pragma unroll
  for (int i = 0; i < 4; i++){
    int ent = rows[ty*4+i];
    if (ent < 0) continue;
    float wgt = tw[ent];
#pragma unroll
    for (int j = 0; j < 4; j++)
      down[(size_t)ent*2048 + n0 + tx*4 + j] = acc[i][j]*wgt;
  }
}

// ---------------- combine 4 expert slots ----------------
__global__ __launch_bounds__(256) void moe_combine(const float* __restrict__ down,
                                                   float* __restrict__ routed){
  int t = blockIdx.x;
  size_t base = (size_t)t*4*2048;
  for (int d = threadIdx.x; d < 2048; d += 256){
    float s = down[base+d] + down[base+2048+d] + down[base+4096+d] + down[base+6144+d];
    routed[(size_t)t*2048 + d] = s;
  }
}

// ---------------- shared-expert silu ----------------
__global__ __launch_bounds__(256) void silu_kernel(const float* __restrict__ sgu,
                                                   float* __restrict__ shact){
  int t = blockIdx.x;
  for (int j = threadIdx.x; j < SHMI; j += 256){
    float g = sgu[(size_t)t*2*SHMI + j], u = sgu[(size_t)t*2*SHMI + SHMI + j];
    shact[(size_t)t*SHMI + j] = g/(1.f+expf(-g))*u;
  }
}

// ---------------- host ----------------
static void launch_gemm(const float* A, int lda, const float* B, int ldb,
                        float* C, int ldc, const float* addsrc, int ldadd,
                        int M, int N, int K, float alpha, hipStream_t stream){
  if (N >= 256){
    dim3 grid((N+127)/128, (M+127)/128);
    gemm_f32_128<<<grid, 256, 0, stream>>>(A, lda, B, ldb, C, ldc, addsrc, ldadd, M, N, K, alpha);
  } else {
    dim3 grid((N+63)/64, (M+63)/64);
    gemm_f32<<<grid, 256, 0, stream>>>(A, lda, B, ldb, C, ldc, addsrc, ldadd, M, N, K, alpha);
  }
}

extern "C" void kernel_launch(void* const* d_in, const int* in_sizes, int n_in,
                              void* d_out, int out_size, void* d_ws, size_t ws_size,
                              hipStream_t stream){
  const int*   positions  = (const int*)  d_in[0];
  const float* hidden     = (const float*)d_in[1];
  const float* ln1_w      = (const float*)d_in[2];
  const float* ln2_w      = (const float*)d_in[3];
  const float* w_qkv_a    = (const float*)d_in[4];
  const float* q_a_ln_w   = (const float*)d_in[5];
  const float* kv_a_ln_w  = (const float*)d_in[6];
  const float* w_q_b      = (const float*)d_in[7];
  const float* w_kv_b     = (const float*)d_in[8];
  const float* w_o        = (const float*)d_in[9];
  const float* w_idx_k    = (const float*)d_in[10];
  const float* idx_k_ln_w = (const float*)d_in[11];
  const float* idx_k_ln_b = (const float*)d_in[12];
  const float* w_idx_qb   = (const float*)d_in[13];
  const float* w_idx_w    = (const float*)d_in[14];
  const float* w_gate     = (const float*)d_in[15];
  const float* w_moe_gu   = (const float*)d_in[16];
  const float* w_moe_d    = (const float*)d_in[17];
  const float* w_sh_gu    = (const float*)d_in[18];
  const float* w_sh_d     = (const float*)d_in[19];

  float* out_final = (float*)d_out;                          // [T,HID]
  float* residual  = (float*)d_out + (size_t)T_TOK*HIDN;     // [T,HID]

  float* ws = (float*)d_ws;
  size_t off = 0;
  float* h      = ws + off; off += 4194304;                  // [T,2048]
  size_t offA = off;
  float* qkv    = ws + offA;                                 // [T,2112]
  float* qbuf   = qkv + 4325376;                             // [T,16,192]
  float* idx_q  = qbuf + 6291456;                            // [T,16,128]
  float* iscores= idx_q + 4194304;                           // [T,T]
  off = offA + 19005440;
  float* down_buf = ws + offA;                               // [T*4,2048] overlay
  size_t offB = off;
  float* q_c    = ws + offB;                                 // [T,1536]
  float* kv_c   = q_c + 3145728;                             // [T,512]
  float* act_buf= ws + offB;                                 // [T*4,512] overlay
  off = offB + 4194304;
  float* k_pe   = ws + off; off += 131072;                   // [T,64]
  float* idx_k  = ws + off; off += 262144;                   // [T,128]
  float* idx_w  = ws + off; off += 32768;                    // [T,16]
  float* kv     = ws + off; off += 8388608;                  // [T,16,256]
  float* attn   = ws + off; off += 4194304;                  // [T,2048]
  float* sgu    = attn;                                      // overlay
  float* shact  = ws + off; off += 2097152;                  // [T,1024]
  float* routed = ws + off; off += 4194304;                  // [T,2048]
  float* glog   = ws + off; off += 16384;                    // [T,8]
  float* tw     = ws + off; off += 8192;                     // [T,4]
  float* ctab   = ws + off; off += 65536;                    // [T,32]
  float* stab   = ws + off; off += 65536;                    // [T,32]
  int* list     = (int*)(ws + off);                          // [T,512]
  int* cnt      = list + 1048576;                            // [T]
  int* ecnt     = cnt + 2048;                                // [8]
  int* elist    = ecnt + 8;                                  // [8,2048]
  size_t total_bytes = (off + 1067016) * sizeof(float);
  if (ws_size < total_bytes) return;

  rope_table_kernel<<<T_TOK, 32, 0, stream>>>(positions, ctab, stab);
  rmsnorm_kernel<<<T_TOK, 256, 0, stream>>>(hidden, HIDN, 0, ln1_w, h, HIDN, HIDN);
  launch_gemm(h, HIDN, w_qkv_a, 2112, qkv, 2112, nullptr, 0, T_TOK, 2112, HIDN, 1.f, stream);
  rmsnorm_kernel<<<T_TOK, 256, 0, stream>>>(qkv, 2112, 0,    q_a_ln_w,  q_c,  QLRr,  QLRr);
  rmsnorm_kernel<<<T_TOK, 256, 0, stream>>>(qkv, 2112, QLRr, kv_a_ln_w, kv_c, KVLRr, KVLRr);
  rope_kpe_kernel<<<T_TOK, 32, 0, stream>>>(qkv, ctab, stab, k_pe);
  launch_gemm(h, HIDN, w_idx_k, IHDd, idx_k, IHDd, nullptr, 0, T_TOK, IHDd, HIDN, 1.f, stream);
  ln_rope_idxk_kernel<<<T_TOK, 128, 0, stream>>>(idx_k, idx_k_ln_w, idx_k_ln_b, ctab, stab);
  launch_gemm(q_c, QLRr, w_q_b, NHEAD*QKDd, qbuf, NHEAD*QKDd, nullptr, 0, T_TOK, NHEAD*QKDd, QLRr, 1.f, stream);
  rope_q_kernel<<<T_TOK, 256, 0, stream>>>(qbuf, ctab, stab);
  launch_gemm(q_c, QLRr, w_idx_qb, INHh*IHDd, idx_q, INHh*IHDd, nullptr, 0, T_TOK, INHh*IHDd, QLRr, 1.f, stream);
  rope_idxq_kernel<<<T_TOK, 256, 0, stream>>>(idx_q, ctab, stab);
  launch_gemm(h, HIDN, w_idx_w, INHh, idx_w, INHh, nullptr, 0, T_TOK, INHh, HIDN, 0.02209708691207961f, stream);
  iscores_kernel<<<dim3(32,32), 256, 0, stream>>>(idx_q, idx_k, idx_w, iscores);
  topk_kernel<<<T_TOK, 256, 0, stream>>>(iscores, list, cnt);
  launch_gemm(kv_c, KVLRr, w_kv_b, NHEAD*(DNn+DVv), kv, NHEAD*(DNn+DVv), nullptr, 0, T_TOK, NHEAD*(DNn+DVv), KVLRr, 1.f, stream);
  attn_kernel<<<dim3(T_TOK, NHEAD/HG), 256, 0, stream>>>(qbuf, kv, k_pe, list, cnt, attn);
  launch_gemm(attn, NHEAD*DVv, w_o, HIDN, residual, HIDN, hidden, HIDN, T_TOK, HIDN, NHEAD*DVv, 1.f, stream);
  rmsnorm_kernel<<<T_TOK, 256, 0, stream>>>(residual, HIDN, 0, ln2_w, h, HIDN, HIDN);
  launch_gemm(h, HIDN, w_gate, NEXP, glog, NEXP, nullptr, 0, T_TOK, NEXP, HIDN, 1.f, stream);
  hipMemsetAsync(ecnt, 0, NEXP*sizeof(int), stream);
  gate_kernel<<<8, 256, 0, stream>>>(glog, tw, ecnt, elist);
  moe_gemm1<<<dim3(8, 32, NEXP), 256, 0, stream>>>(h, w_moe_gu, ecnt, elist, act_buf);
  moe_gemm2<<<dim3(32, 32, NEXP), 256, 0, stream>>>(act_buf, w_moe_d, ecnt, elist, tw, down_buf);
  moe_combine<<<T_TOK, 256, 0, stream>>>(down_buf, routed);
  launch_gemm(h, HIDN, w_sh_gu, 2*SHMI, sgu, 2*SHMI, nullptr, 0, T_TOK, 2*SHMI, HIDN, 1.f, stream);
  silu_kernel<<<T_TOK, 256, 0, stream>>>(sgu, shact);
  launch_gemm(shact, SHMI, w_sh_d, HIDN, out_final, HIDN, routed, HIDN, T_TOK, HIDN, SHMI, 1.f, stream);
  (void)in_sizes; (void)n_in; (void)out_size;
}

// Round 5
// 4483.153 us; speedup vs baseline: 1.2674x; 1.2499x over previous
//
#include <hip/hip_runtime.h>
#include <cstdint>
#include <cstddef>

#define T_TOK 2048
#define HIDN  2048
#define NHEAD 16
#define QLRr  1536
#define KVLRr 512
#define DNn   128
#define DRr   64
#define DVv   128
#define QKDd  192
#define INHh  16
#define IHDd  128
#define ITOPKk 512
#define NEXP  8
#define MIi   512
#define SHMI  1024
#define EPSF  1e-6f
#define NEGINF (-3.402823466e38f)

typedef __attribute__((ext_vector_type(8))) short short8;
typedef __attribute__((ext_vector_type(4))) float float4v;

// ---------------- helpers ----------------
__device__ __forceinline__ float warp_sum(float v){
#pragma unroll
  for (int off=32; off>0; off>>=1) v += __shfl_down(v, off, 64);
  return v;
}
__device__ __forceinline__ float warp_max(float v){
#pragma unroll
  for (int off=32; off>0; off>>=1) v = fmaxf(v, __shfl_down(v, off, 64));
  return v;
}
__device__ __forceinline__ unsigned mapf(float f){
  unsigned b = __float_as_uint(f);
  if ((b<<1)==0u) b = 0u;
  return (b & 0x80000000u) ? ~b : (b | 0x80000000u);
}
__device__ __forceinline__ ushort f2bf(float f){
  unsigned u = __float_as_uint(f);
  unsigned r = (u + 0x7fffu + ((u>>16)&1u)) >> 16;
  return (ushort)r;
}

// ---------------- rope tables ----------------
__global__ void rope_table_kernel(const int* __restrict__ pos,
                                  float* __restrict__ ct, float* __restrict__ st){
  int t = blockIdx.x, j = threadIdx.x;          // blockDim 32
  float inv = powf(10000.0f, -(float)j * (1.0f/32.0f));
  float f = (float)pos[t] * inv;
  ct[t*32+j] = cosf(f);
  st[t*32+j] = sinf(f);
}

// ---------------- rmsnorm ----------------
__global__ __launch_bounds__(256) void rmsnorm_kernel(
    const float* __restrict__ x, int xstride, int xoff,
    const float* __restrict__ w, float* __restrict__ out, int ostride, int D){
  int t = blockIdx.x, tid = threadIdx.x;
  const float* xp = x + (size_t)t*xstride + xoff;
  const float4* x4 = (const float4*)xp;
  int D4 = D >> 2;
  float ss = 0.f;
  for (int i = tid; i < D4; i += 256){ float4 v = x4[i]; ss += v.x*v.x+v.y*v.y+v.z*v.z+v.w*v.w; }
  __shared__ float red[4];
  float s = warp_sum(ss);
  int lane = tid & 63, wid = tid >> 6;
  if (lane==0) red[wid] = s;
  __syncthreads();
  if (tid==0) red[0] = red[0]+red[1]+red[2]+red[3];
  __syncthreads();
  float sc = rsqrtf(red[0]/(float)D + EPSF);
  const float4* w4 = (const float4*)w;
  float4* o4 = (float4*)(out + (size_t)t*ostride);
  for (int i = tid; i < D4; i += 256){
    float4 v = x4[i], ww = w4[i];
    float4 r; r.x=v.x*sc*ww.x; r.y=v.y*sc*ww.y; r.z=v.z*sc*ww.z; r.w=v.w*sc*ww.w;
    o4[i] = r;
  }
}

// ---------------- k_pe rope ----------------
__global__ void rope_kpe_kernel(const float* __restrict__ qkv,
                                const float* __restrict__ ct, const float* __restrict__ st,
                                float* __restrict__ kpe){
  int t = blockIdx.x, j = threadIdx.x;          // blockDim 32
  const float* x = qkv + (size_t)t*2112 + 2048;
  float x1 = x[j], x2 = x[32+j];
  float c = ct[t*32+j], sn = st[t*32+j];
  kpe[t*64+j]    = x1*c - x2*sn;
  kpe[t*64+32+j] = x1*sn + x2*c;
}

// ---------------- idx_k layernorm + rope ----------------
__global__ __launch_bounds__(128) void ln_rope_idxk_kernel(
    float* __restrict__ xk, const float* __restrict__ w, const float* __restrict__ b,
    const float* __restrict__ ct, const float* __restrict__ st){
  int t = blockIdx.x, tid = threadIdx.x;
  float v = xk[(size_t)t*IHDd + tid];
  float s1 = warp_sum(v), s2 = warp_sum(v*v);
  __shared__ float r1[2], r2[2];
  int lane = tid & 63, wid = tid >> 6;
  if (lane==0){ r1[wid]=s1; r2[wid]=s2; }
  __syncthreads();
  float mean = (r1[0]+r1[1]) * (1.f/128.f);
  float var  = (r2[0]+r2[1]) * (1.f/128.f) - mean*mean;
  float y = (v-mean)*rsqrtf(var+EPSF)*w[tid]+b[tid];
  __shared__ float ly[128];
  ly[tid] = y; __syncthreads();
  float o;
  if (tid < 64) o = y;
  else if (tid < 96){ int j = tid-64; o = ly[64+j]*ct[t*32+j] - ly[96+j]*st[t*32+j]; }
  else              { int j = tid-96; o = ly[64+j]*st[t*32+j] + ly[96+j]*ct[t*32+j]; }
  xk[(size_t)t*IHDd + tid] = o;
}

// ---------------- rope over q ----------------
__global__ __launch_bounds__(256) void rope_q_kernel(float* __restrict__ q,
                                  const float* __restrict__ ct, const float* __restrict__ st){
  int t = blockIdx.x, tid = threadIdx.x;
  __shared__ float c[32], s[32];
  if (tid < 32){ c[tid]=ct[t*32+tid]; s[tid]=st[t*32+tid]; }
  __syncthreads();
  for (int idx = tid; idx < NHEAD*32; idx += 256){
    int hh = idx >> 5, j = idx & 31;
    float* base = q + (size_t)t*(NHEAD*QKDd) + hh*QKDd;
    float x1 = base[DNn+j], x2 = base[DNn+32+j];
    base[DNn+j]    = x1*c[j] - x2*s[j];
    base[DNn+32+j] = x1*s[j] + x2*c[j];
  }
}

// ---------------- rope over idx_q ----------------
__global__ __launch_bounds__(256) void rope_idxq_kernel(float* __restrict__ q,
                                  const float* __restrict__ ct, const float* __restrict__ st){
  int t = blockIdx.x, tid = threadIdx.x;
  __shared__ float c[32], s[32];
  if (tid < 32){ c[tid]=ct[t*32+tid]; s[tid]=st[t*32+tid]; }
  __syncthreads();
  for (int idx = tid; idx < INHh*32; idx += 256){
    int hh = idx >> 5, j = idx & 31;
    float* base = q + (size_t)t*(INHh*IHDd) + hh*IHDd;
    float x1 = base[64+j], x2 = base[96+j];
    base[64+j] = x1*c[j] - x2*s[j];
    base[96+j] = x1*s[j] + x2*c[j];
  }
}

// ---------------- fp32 GEMM, 64x64 tile ----------------
__global__ __launch_bounds__(256) void gemm_f32(
    const float* __restrict__ A, int lda,
    const float* __restrict__ B, int ldb,
    float* __restrict__ C, int ldc,
    const float* __restrict__ addsrc, int ldadd,
    int M, int N, int K, float alpha){
  __shared__ float As[16][68];
  __shared__ float Bs[16][68];
  int tid = threadIdx.x;
  int tx = tid & 15, ty = tid >> 4;
  int m0 = blockIdx.y*64, n0 = blockIdx.x*64;
  float acc[4][4] = {};
  for (int k0 = 0; k0 < K; k0 += 16){
#pragma unroll
    for (int i = 0; i < 4; i++){
      int lin = tid + i*256; int r = lin >> 4, c = lin & 15;
      int m = m0 + r;
      As[c][r] = (m < M) ? A[(size_t)m*lda + k0 + c] : 0.f;
    }
#pragma unroll
    for (int i = 0; i < 4; i++){
      int lin = tid + i*256; int kk = lin >> 6, c = lin & 63;
      int n = n0 + c;
      Bs[kk][c] = (n < N) ? B[(size_t)(k0+kk)*ldb + n] : 0.f;
    }
    __syncthreads();
#pragma unroll
    for (int kk = 0; kk < 16; kk++){
      float4 av = *(const float4*)&As[kk][ty*4];
      float4 bv = *(const float4*)&Bs[kk][tx*4];
      float a[4] = {av.x, av.y, av.z, av.w};
      float b[4] = {bv.x, bv.y, bv.z, bv.w};
#pragma unroll
      for (int i = 0; i < 4; i++)
#pragma unroll
        for (int j = 0; j < 4; j++) acc[i][j] += a[i]*b[j];
    }
    __syncthreads();
  }
#pragma unroll
  for (int i = 0; i < 4; i++){
    int m = m0 + ty*4 + i;
    if (m >= M) continue;
#pragma unroll
    for (int j = 0; j < 4; j++){
      int n = n0 + tx*4 + j;
      if (n >= N) continue;
      float v = acc[i][j]*alpha;
      if (addsrc) v += addsrc[(size_t)m*ldadd + n];
      C[(size_t)m*ldc + n] = v;
    }
  }
}

// ---------------- fp32 GEMM, 128x128 tile ----------------
__device__ __forceinline__ int bswz(int col){ return col + ((col >> 5) << 2); }

__global__ __launch_bounds__(256) void gemm_f32_128(
    const float* __restrict__ A, int lda,
    const float* __restrict__ B, int ldb,
    float* __restrict__ C, int ldc,
    const float* __restrict__ addsrc, int ldadd,
    int M, int N, int K, float alpha){
  __shared__ float As[16][132];
  __shared__ float Bs[16][144];
  int tid = threadIdx.x;
  int tx = tid & 15, ty = tid >> 4;
  int m0 = blockIdx.y*128, n0 = blockIdx.x*128;
  int pc0 = bswz(tx*8);
  float acc[8][8] = {};
  for (int k0 = 0; k0 < K; k0 += 16){
#pragma unroll
    for (int i = 0; i < 2; i++){
      int f = tid + i*256; int r = f >> 2, kq = f & 3;
      float4 v = {0,0,0,0};
      if (m0 + r < M) v = *(const float4*)(A + (size_t)(m0+r)*lda + k0 + kq*4);
      As[kq*4+0][r]=v.x; As[kq*4+1][r]=v.y; As[kq*4+2][r]=v.z; As[kq*4+3][r]=v.w;
    }
#pragma unroll
    for (int i = 0; i < 2; i++){
      int f = tid + i*256; int kk = f >> 5, nq = f & 31;
      int n = n0 + nq*4;
      const float* bp = B + (size_t)(k0+kk)*ldb + n;
      float4 v;
      if (n + 3 < N) v = *(const float4*)bp;
      else { v.x = (n<N)?bp[0]:0.f; v.y = (n+1<N)?bp[1]:0.f; v.z = (n+2<N)?bp[2]:0.f; v.w = (n+3<N)?bp[3]:0.f; }
      *(float4*)&Bs[kk][bswz(nq*4)] = v;
    }
    __syncthreads();
#pragma unroll
    for (int kk = 0; kk < 16; kk++){
      float4 a0 = *(const float4*)&As[kk][ty*8];
      float4 a1 = *(const float4*)&As[kk][ty*8+4];
      float4 b0 = *(const float4*)&Bs[kk][pc0];
      float4 b1 = *(const float4*)&Bs[kk][pc0+4];
      float a[8] = {a0.x,a0.y,a0.z,a0.w,a1.x,a1.y,a1.z,a1.w};
      float b[8] = {b0.x,b0.y,b0.z,b0.w,b1.x,b1.y,b1.z,b1.w};
#pragma unroll
      for (int i = 0; i < 8; i++)
#pragma unroll
        for (int j = 0; j < 8; j++) acc[i][j] += a[i]*b[j];
    }
    __syncthreads();
  }
  bool fullN = (n0 + 128 <= N);
#pragma unroll
  for (int i = 0; i < 8; i++){
    int m = m0 + ty*8 + i;
    if (m >= M) continue;
    if (fullN){
      float* cp = C + (size_t)m*ldc + n0 + tx*8;
      float4 o0, o1;
      o0.x=acc[i][0]*alpha; o0.y=acc[i][1]*alpha; o0.z=acc[i][2]*alpha; o0.w=acc[i][3]*alpha;
      o1.x=acc[i][4]*alpha; o1.y=acc[i][5]*alpha; o1.z=acc[i][6]*alpha; o1.w=acc[i][7]*alpha;
      if (addsrc){
        const float* ap = addsrc + (size_t)m*ldadd + n0 + tx*8;
        float4 s0 = *(const float4*)ap, s1 = *(const float4*)(ap+4);
        o0.x+=s0.x; o0.y+=s0.y; o0.z+=s0.z; o0.w+=s0.w;
        o1.x+=s1.x; o1.y+=s1.y; o1.z+=s1.z; o1.w+=s1.w;
      }
      *(float4*)cp = o0; *(float4*)(cp+4) = o1;
    } else {
#pragma unroll
      for (int j = 0; j < 8; j++){
        int n = n0 + tx*8 + j;
        if (n >= N) continue;
        float v = acc[i][j]*alpha;
        if (addsrc) v += addsrc[(size_t)m*ldadd + n];
        C[(size_t)m*ldc + n] = v;
      }
    }
  }
}

// ---------------- convert fp32 -> bf16 ----------------
__global__ __launch_bounds__(256) void conv_bf16(const float* __restrict__ in,
                                                 ushort* __restrict__ out, int n4){
  int i = blockIdx.x*256 + threadIdx.x;
  if (i < n4){
    float4 v = ((const float4*)in)[i];
    ushort4 o; o.x=f2bf(v.x); o.y=f2bf(v.y); o.z=f2bf(v.z); o.w=f2bf(v.w);
    ((ushort4*)out)[i] = o;
  }
}

// ---------------- transpose + convert: src[K,N] fp32 -> dst[N,K] bf16 ----------------
__global__ __launch_bounds__(256) void transconv(const float* __restrict__ src0,
                                                 ushort* __restrict__ dst0, int K, int N){
  int e = blockIdx.z;
  const float* src = src0 + (size_t)e*K*N;
  ushort* dst = dst0 + (size_t)e*N*K;
  int k0 = blockIdx.y*32, n0 = blockIdx.x*32;
  __shared__ float tile[32][33];
  int c = threadIdx.x & 31, r = threadIdx.x >> 5;
  for (int rr = r; rr < 32; rr += 8) tile[rr][c] = src[(size_t)(k0+rr)*N + n0 + c];
  __syncthreads();
  for (int rr = r; rr < 32; rr += 8) dst[(size_t)(n0+rr)*K + k0 + c] = f2bf(tile[c][rr]);
}

// ===== reg-staged bf16 MFMA GEMM: C[M,N] = A[M,K] @ Bt[N,K]^T (+addsrc) =====
template<int OUTBF>
__global__ __launch_bounds__(256) void gemm_bf16s(
    const ushort* __restrict__ A, const ushort* __restrict__ Bt,
    float* __restrict__ Cf, ushort* __restrict__ Cb,
    const float* __restrict__ addsrc, int N, int K){
  __shared__ __align__(16) ushort As[5120];
  __shared__ __align__(16) ushort Bs[5120];
  int tid = threadIdx.x, lane = tid & 63, w = tid >> 6;
  int m0 = blockIdx.y*128, n0 = blockIdx.x*128;
  int wr = w >> 1, wc = w & 1;
  int r15 = lane & 15, g = lane >> 4;
  int srow = tid >> 1, sh = (tid & 1) << 4;
  const ushort* Ag = A + (size_t)(m0 + srow)*K + sh;
  const ushort* Bg = Bt + (size_t)(n0 + srow)*K + sh;
  ushort* Asw = &As[srow*40 + sh];
  ushort* Bsw = &Bs[srow*40 + sh];
  int aoff[4], boff[4];
#pragma unroll
  for (int m = 0; m < 4; m++){
    aoff[m] = (wr*64 + m*16 + r15)*40 + g*8;
    boff[m] = (wc*64 + m*16 + r15)*40 + g*8;
  }
  float4v acc[4][4];
#pragma unroll
  for (int i=0;i<4;i++)
#pragma unroll
    for (int j=0;j<4;j++) acc[i][j] = (float4v){0.f,0.f,0.f,0.f};
  int nk = K >> 5;
  for (int kt = 0; kt < nk; kt++){
    int k0 = kt << 5;
    short8 a0 = *(const short8*)(Ag + k0);
    short8 a1 = *(const short8*)(Ag + k0 + 8);
    short8 b0 = *(const short8*)(Bg + k0);
    short8 b1 = *(const short8*)(Bg + k0 + 8);
    __syncthreads();
    *(short8*)Asw = a0; *(short8*)(Asw + 8) = a1;
    *(short8*)Bsw = b0; *(short8*)(Bsw + 8) = b1;
    __syncthreads();
    short8 av[4], bv[4];
#pragma unroll
    for (int m = 0; m < 4; m++) av[m] = *(const short8*)&As[aoff[m]];
#pragma unroll
    for (int n = 0; n < 4; n++) bv[n] = *(const short8*)&Bs[boff[n]];
#pragma unroll
    for (int m = 0; m < 4; m++)
#pragma unroll
      for (int n = 0; n < 4; n++)
        acc[m][n] = __builtin_amdgcn_mfma_f32_16x16x32_bf16(av[m], bv[n], acc[m][n], 0, 0, 0);
  }
#pragma unroll
  for (int m = 0; m < 4; m++){
    int row0 = m0 + wr*64 + m*16 + g*4;
#pragma unroll
    for (int n = 0; n < 4; n++){
      int col = n0 + wc*64 + n*16 + r15;
#pragma unroll
      for (int r = 0; r < 4; r++){
        float v = acc[m][n][r];
        size_t o = (size_t)(row0 + r)*N + col;
        if (addsrc) v += addsrc[o];
        if (OUTBF) Cb[o] = f2bf(v);
        else       Cf[o] = v;
      }
    }
  }
}

// ===== MoE GEMM1 (gathered rows of h2_bf) -> gu fp32 [8192,1024] =====
__global__ __launch_bounds__(256) void moe_gemm1s(
    const ushort* __restrict__ h2bf, const ushort* __restrict__ wgut,
    const int* __restrict__ ecnt, const int* __restrict__ elist,
    float* __restrict__ gu){
  int e = blockIdx.z;
  int count = ecnt[e];
  int r0 = blockIdx.y*128;
  if (r0 >= count) return;
  __shared__ int rows[128];
  __shared__ __align__(16) ushort As[5120];
  __shared__ __align__(16) ushort Bs[5120];
  int tid = threadIdx.x, lane = tid & 63, w = tid >> 6;
  int n0 = blockIdx.x*128;
  if (tid < 128) rows[tid] = (r0 + tid < count) ? elist[e*2048 + r0 + tid] : -1;
  __syncthreads();
  int wr = w >> 1, wc = w & 1;
  int r15 = lane & 15, g = lane >> 4;
  int srow = tid >> 1, sh = (tid & 1) << 4;
  int ent0 = rows[srow];
  int tok = (ent0 >= 0) ? (ent0 >> 2) : 0;
  const ushort* Ag = h2bf + (size_t)tok*2048 + sh;
  const ushort* Bg = wgut + ((size_t)e*1024 + n0 + srow)*2048 + sh;
  ushort* Asw = &As[srow*40 + sh];
  ushort* Bsw = &Bs[srow*40 + sh];
  int aoff[4], boff[4];
#pragma unroll
  for (int m = 0; m < 4; m++){
    aoff[m] = (wr*64 + m*16 + r15)*40 + g*8;
    boff[m] = (wc*64 + m*16 + r15)*40 + g*8;
  }
  float4v acc[4][4];
#pragma unroll
  for (int i=0;i<4;i++)
#pragma unroll
    for (int j=0;j<4;j++) acc[i][j] = (float4v){0.f,0.f,0.f,0.f};
  for (int kt = 0; kt < 64; kt++){
    int k0 = kt << 5;
    short8 a0 = *(const short8*)(Ag + k0);
    short8 a1 = *(const short8*)(Ag + k0 + 8);
    short8 b0 = *(const short8*)(Bg + k0);
    short8 b1 = *(const short8*)(Bg + k0 + 8);
    __syncthreads();
    *(short8*)Asw = a0; *(short8*)(Asw + 8) = a1;
    *(short8*)Bsw = b0; *(short8*)(Bsw + 8) = b1;
    __syncthreads();
    short8 av[4], bv[4];
#pragma unroll
    for (int m = 0; m < 4; m++) av[m] = *(const short8*)&As[aoff[m]];
#pragma unroll
    for (int n = 0; n < 4; n++) bv[n] = *(const short8*)&Bs[boff[n]];
#pragma unroll
    for (int m = 0; m < 4; m++)
#pragma unroll
      for (int n = 0; n < 4; n++)
        acc[m][n] = __builtin_amdgcn_mfma_f32_16x16x32_bf16(av[m], bv[n], acc[m][n], 0, 0, 0);
  }
#pragma unroll
  for (int m = 0; m < 4; m++){
#pragma unroll
    for (int r = 0; r < 4; r++){
      int ent = rows[wr*64 + m*16 + g*4 + r];
      if (ent < 0) continue;
#pragma unroll
      for (int n = 0; n < 4; n++){
        int col = n0 + wc*64 + n*16 + r15;
        gu[(size_t)ent*1024 + col] = acc[m][n][r];
      }
    }
  }
}

// ===== MoE GEMM2: act_bf -> down fp32 [8192,2048] (x tw) =====
__global__ __launch_bounds__(256) void moe_gemm2s(
    const ushort* __restrict__ act, const ushort* __restrict__ wdt,
    const int* __restrict__ ecnt, const int* __restrict__ elist,
    const float* __restrict__ tw, float* __restrict__ down){
  int e = blockIdx.z;
  int count = ecnt[e];
  int r0 = blockIdx.y*128;
  if (r0 >= count) return;
  __shared__ int rows[128];
  __shared__ __align__(16) ushort As[5120];
  __shared__ __align__(16) ushort Bs[5120];
  int tid = threadIdx.x, lane = tid & 63, w = tid >> 6;
  int n0 = blockIdx.x*128;
  if (tid < 128) rows[tid] = (r0 + tid < count) ? elist[e*2048 + r0 + tid] : -1;
  __syncthreads();
  int wr = w >> 1, wc = w & 1;
  int r15 = lane & 15, g = lane >> 4;
  int srow = tid >> 1, sh = (tid & 1) << 4;
  int ent0 = rows[srow];
  int src = (ent0 >= 0) ? ent0 : 0;
  const ushort* Ag = act + (size_t)src*512 + sh;
  const ushort* Bg = wdt + ((size_t)e*2048 + n0 + srow)*512 + sh;
  ushort* Asw = &As[srow*40 + sh];
  ushort* Bsw = &Bs[srow*40 + sh];
  int aoff[4], boff[4];
#pragma unroll
  for (int m = 0; m < 4; m++){
    aoff[m] = (wr*64 + m*16 + r15)*40 + g*8;
    boff[m] = (wc*64 + m*16 + r15)*40 + g*8;
  }
  float4v acc[4][4];
#pragma unroll
  for (int i=0;i<4;i++)
#pragma unroll
    for (int j=0;j<4;j++) acc[i][j] = (float4v){0.f,0.f,0.f,0.f};
  for (int kt = 0; kt < 16; kt++){
    int k0 = kt << 5;
    short8 a0 = *(const short8*)(Ag + k0);
    short8 a1 = *(const short8*)(Ag + k0 + 8);
    short8 b0 = *(const short8*)(Bg + k0);
    short8 b1 = *(const short8*)(Bg + k0 + 8);
    __syncthreads();
    *(short8*)Asw = a0; *(short8*)(Asw + 8) = a1;
    *(short8*)Bsw = b0; *(short8*)(Bsw + 8) = b1;
    __syncthreads();
    short8 av[4], bv[4];
#pragma unroll
    for (int m = 0; m < 4; m++) av[m] = *(const short8*)&As[aoff[m]];
#pragma unroll
    for (int n = 0; n < 4; n++) bv[n] = *(const short8*)&Bs[boff[n]];
#pragma unroll
    for (int m = 0; m < 4; m++)
#pragma unroll
      for (int n = 0; n < 4; n++)
        acc[m][n] = __builtin_amdgcn_mfma_f32_16x16x32_bf16(av[m], bv[n], acc[m][n], 0, 0, 0);
  }
#pragma unroll
  for (int m = 0; m < 4; m++){
#pragma unroll
    for (int r = 0; r < 4; r++){
      int ent = rows[wr*64 + m*16 + g*4 + r];
      if (ent < 0) continue;
      float wgt = tw[ent];
#pragma unroll
      for (int n = 0; n < 4; n++){
        int col = n0 + wc*64 + n*16 + r15;
        down[(size_t)ent*2048 + col] = acc[m][n][r]*wgt;
      }
    }
  }
}

// ---------------- indexer scores (fp32, causal tiles) ----------------
__global__ __launch_bounds__(256) void iscores_kernel(
    const float* __restrict__ idx_q, const float* __restrict__ idx_k,
    const float* __restrict__ idx_w, float* __restrict__ sc){
  int sb = blockIdx.x, tb = blockIdx.y;
  if (sb > tb) return;
  int t0 = tb*64, s0 = sb*64;
  __shared__ float As[32][68];
  __shared__ float Bs[32][68];
  __shared__ float Ws[64][17];
  int tid = threadIdx.x, tx = tid & 15, ty = tid >> 4;
  for (int i = tid; i < 1024; i += 256){ int r = i >> 4, hh = i & 15; Ws[r][hh] = idx_w[(size_t)(t0+r)*16 + hh]; }
  float sco[4][4] = {};
  for (int h = 0; h < 16; h++){
    float acc[4][4] = {};
    for (int k0 = 0; k0 < 128; k0 += 32){
#pragma unroll
      for (int i = 0; i < 8; i++){
        int lin = tid + i*256; int r = lin >> 5, c = lin & 31;
        As[c][r] = idx_q[(size_t)(t0+r)*2048 + h*128 + k0 + c];
      }
#pragma unroll
      for (int i = 0; i < 8; i++){
        int lin = tid + i*256; int r = lin >> 5, c = lin & 31;
        Bs[c][r] = idx_k[(size_t)(s0+r)*128 + k0 + c];
      }
      __syncthreads();
#pragma unroll
      for (int kk = 0; kk < 32; kk++){
        float4 av = *(const float4*)&As[kk][ty*4];
        float4 bv = *(const float4*)&Bs[kk][tx*4];
        float a[4] = {av.x, av.y, av.z, av.w};
        float b[4] = {bv.x, bv.y, bv.z, bv.w};
#pragma unroll
        for (int i = 0; i < 4; i++)
#pragma unroll
          for (int j = 0; j < 4; j++) acc[i][j] += a[i]*b[j];
      }
      __syncthreads();
    }
#pragma unroll
    for (int i = 0; i < 4; i++){
      float wv = Ws[ty*4+i][h];
#pragma unroll
      for (int j = 0; j < 4; j++) sco[i][j] += wv * fmaxf(acc[i][j], 0.f);
    }
  }
#pragma unroll
  for (int i = 0; i < 4; i++){
    int tg = t0 + ty*4 + i;
#pragma unroll
    for (int j = 0; j < 4; j++){
      int sg = s0 + tx*4 + j;
      sc[(size_t)tg*2048 + sg] = (sg <= tg) ? sco[i][j] : NEGINF;
    }
  }
}

// ---------------- top-k (stable ties) ----------------
__global__ __launch_bounds__(256) void topk_kernel(
    const float* __restrict__ scores, int* __restrict__ list, int* __restrict__ cnt){
  int t = blockIdx.x, tid = threadIdx.x;
  if (t < ITOPKk){
    for (int i = tid; i <= t; i += 256) list[(size_t)t*ITOPKk + i] = i;
    if (tid==0) cnt[t] = t+1;
    return;
  }
  int n = t+1;
  const float* row = scores + (size_t)t*2048;
  __shared__ unsigned hist[256];
  __shared__ unsigned sh_prefix, sh_krem;
  __shared__ int scan[256];
  __shared__ int sh_base_sel, sh_base_eq;
  if (tid==0){ sh_prefix = 0u; sh_krem = ITOPKk; }
  __syncthreads();
  for (int level = 3; level >= 0; level--){
    int shift = level*8;
    hist[tid] = 0u; __syncthreads();
    unsigned pfx = sh_prefix;
    for (int s = tid; s < n; s += 256){
      unsigned u = mapf(row[s]);
      bool ok = (level==3) || ((u >> (shift+8)) == pfx);
      if (ok) atomicAdd(&hist[(u >> shift) & 255u], 1u);
    }
    __syncthreads();
    if (tid==0){
      unsigned krem = sh_krem, c = 0u; int bsel = 0;
      for (int b = 255; b >= 0; b--){
        if (c + hist[b] >= krem){ bsel = b; break; }
        c += hist[b];
      }
      sh_prefix = (pfx << 8) | (unsigned)bsel;
      sh_krem = krem - c;
    }
    __syncthreads();
  }
  unsigned uth = sh_prefix; int R = (int)sh_krem;
  if (tid==0){ sh_base_sel = 0; sh_base_eq = 0; }
  __syncthreads();
  for (int c0 = 0; c0 < n; c0 += 256){
    int s = c0 + tid;
    unsigned u = (s < n) ? mapf(row[s]) : 0u;
    int gt = (s < n) && (u > uth);
    int eq = (s < n) && (u == uth);
    scan[tid] = (eq << 16) | gt; __syncthreads();
    for (int off = 1; off < 256; off <<= 1){
      int v = (tid >= off) ? scan[tid-off] : 0; __syncthreads();
      scan[tid] += v; __syncthreads();
    }
    int incl = scan[tid];
    int gt_incl = incl & 0xffff, eq_incl = incl >> 16;
    int gt_excl = gt_incl - gt, eq_excl = eq_incl - eq;
    int tot = scan[255]; int gt_tot = tot & 0xffff, eq_tot = tot >> 16;
    int base_sel = sh_base_sel, base_eq = sh_base_eq;
    int rtake = R - base_eq; if (rtake < 0) rtake = 0;
    bool selected = gt || (eq && eq_excl < rtake);
    int pos = base_sel + gt_excl + min(eq_excl, rtake);
    if (selected) list[(size_t)t*ITOPKk + pos] = s;
    __syncthreads();
    if (tid==0){
      sh_base_sel = base_sel + gt_tot + min(eq_tot, rtake);
      sh_base_eq  = base_eq + eq_tot;
    }
    __syncthreads();
  }
  if (tid==0) cnt[t] = ITOPKk;
}

// ---------------- sparse attention (fp32 kv, fp32 out) ----------------
#define HG 4
__global__ __launch_bounds__(256) void attn_kernel(
    const float* __restrict__ q, const float* __restrict__ kv,
    const float* __restrict__ kpe,
    const int* __restrict__ list, const int* __restrict__ cnt,
    float* __restrict__ attn){
  int t = blockIdx.x, h0 = blockIdx.y*HG;
  int tid = threadIdx.x, lane = tid & 63, w = tid >> 6;
  __shared__ int   sl[ITOPKk];
  __shared__ float qs[HG][200];
  __shared__ float lg[ITOPKk];
  __shared__ float redm[4], reds[4];
  __shared__ float4 outp4[8][32];
  int n = cnt[t];
  for (int i = tid; i < n; i += 256) sl[i] = list[(size_t)t*ITOPKk + i];
  for (int i = tid; i < HG*192; i += 256){
    int hh = i/192, d = i - hh*192;
    qs[hh][d] = q[(size_t)t*(NHEAD*QKDd) + (h0+hh)*QKDd + d];
  }
  __syncthreads();
  const float scale = 0.07216878364870323f;
  int quarter = lane >> 4, s16 = lane & 15;
  int slice = tid & 31, sg = tid >> 5;
  for (int hh = 0; hh < HG; hh++){
    int h = h0 + hh;
    for (int p0 = 0; p0 < n; p0 += 64){
      int i = p0 + w*16 + s16;
      float part = 0.f;
      if (i < n){
        int s = sl[i];
        const float* kp = kv + (size_t)s*4096 + h*256 + quarter*32;
        const float* pp = kpe + (size_t)s*64 + quarter*16;
        const float* qn = &qs[hh][quarter*32];
        const float* qp = &qs[hh][128 + quarter*16];
#pragma unroll
        for (int j = 0; j < 8; j++){
          float4 kvv = *(const float4*)(kp + j*4);
          float4 qv  = *(const float4*)(qn + j*4);
          part += kvv.x*qv.x + kvv.y*qv.y + kvv.z*qv.z + kvv.w*qv.w;
        }
#pragma unroll
        for (int j = 0; j < 4; j++){
          float4 kvv = *(const float4*)(pp + j*4);
          float4 qv  = *(const float4*)(qp + j*4);
          part += kvv.x*qv.x + kvv.y*qv.y + kvv.z*qv.z + kvv.w*qv.w;
        }
      }
      part += __shfl_down(part, 32, 64);
      part += __shfl_down(part, 16, 64);
      if (quarter == 0 && i < n) lg[i] = part*scale;
    }
    __syncthreads();
    float mx = NEGINF;
    for (int i = tid; i < n; i += 256) mx = fmaxf(mx, lg[i]);
    mx = warp_max(mx);
    if (lane==0) redm[w] = mx;
    __syncthreads();
    mx = fmaxf(fmaxf(redm[0],redm[1]), fmaxf(redm[2],redm[3]));
    float sum = 0.f;
    for (int i = tid; i < n; i += 256){ float p = expf(lg[i]-mx); lg[i] = p; sum += p; }
    sum = warp_sum(sum);
    if (lane==0) reds[w] = sum;
    __syncthreads();
    float inv = 1.f/(reds[0]+reds[1]+reds[2]+reds[3]);
    float4 acc = {0,0,0,0};
    for (int i = sg; i < n; i += 8){
      float p = lg[i];
      float4 v4 = *((const float4*)(kv + (size_t)sl[i]*4096 + h*256 + 128) + slice);
      acc.x += p*v4.x; acc.y += p*v4.y; acc.z += p*v4.z; acc.w += p*v4.w;
    }
    outp4[sg][slice] = acc;
    __syncthreads();
    if (tid < 32){
      float4 r = outp4[0][tid];
#pragma unroll
      for (int gg = 1; gg < 8; gg++){
        float4 o = outp4[gg][tid];
        r.x += o.x; r.y += o.y; r.z += o.z; r.w += o.w;
      }
      r.x *= inv; r.y *= inv; r.z *= inv; r.w *= inv;
      *(float4*)&attn[(size_t)t*2048 + h*128 + tid*4] = r;
    }
    __syncthreads();
  }
}

// ---------------- gate ----------------
__global__ void gate_kernel(const float* __restrict__ glog, float* __restrict__ tw,
                            int* __restrict__ ecnt, int* __restrict__ elist){
  int t = blockIdx.x*256 + threadIdx.x;
  if (t >= T_TOK) return;
  float g[8]; float mx = NEGINF;
  for (int i = 0; i < 8; i++){ g[i] = glog[t*8+i]; mx = fmaxf(mx, g[i]); }
  float s = 0.f;
  for (int i = 0; i < 8; i++){ g[i] = expf(g[i]-mx); s += g[i]; }
  for (int i = 0; i < 8; i++) g[i] /= s;
  bool used[8] = {};
  float tv[4]; int si[4];
  for (int k = 0; k < 4; k++){
    float best = -1.f; int bi = 0;
    for (int i = 0; i < 8; i++) if (!used[i] && g[i] > best){ best = g[i]; bi = i; }
    used[bi] = true; tv[k] = best; si[k] = bi;
  }
  float s4 = tv[0]+tv[1]+tv[2]+tv[3];
  for (int k = 0; k < 4; k++){
    tw[t*4+k] = tv[k]/s4;
    int pos = atomicAdd(&ecnt[si[k]], 1);
    elist[si[k]*2048 + pos] = t*4+k;
  }
}

// ---------------- MoE silu: gu [8192,1024] -> act bf16 [8192,512] ----------------
__global__ __launch_bounds__(256) void silu_moe(const float* __restrict__ gu,
                                                ushort* __restrict__ act){
  int i = blockIdx.x*256 + threadIdx.x;
  if (i >= 8192*128) return;
  int row = i >> 7, jc = i & 127;
  float4 g4 = ((const float4*)(gu + (size_t)row*1024))[jc];
  float4 u4 = ((const float4*)(gu + (size_t)row*1024 + 512))[jc];
  ushort4 o;
  o.x = f2bf(g4.x/(1.f+expf(-g4.x))*u4.x);
  o.y = f2bf(g4.y/(1.f+expf(-g4.y))*u4.y);
  o.z = f2bf(g4.z/(1.f+expf(-g4.z))*u4.z);
  o.w = f2bf(g4.w/(1.f+expf(-g4.w))*u4.w);
  ((ushort4*)(act + (size_t)row*512))[jc] = o;
}

// ---------------- combine: out_final += sum of 4 expert slots ----------------
__global__ __launch_bounds__(256) void moe_combine(const float* __restrict__ down,
                                                   float* __restrict__ outf){
  int t = blockIdx.x;
  size_t base = (size_t)t*4*2048;
  for (int d = threadIdx.x; d < 2048; d += 256){
    float s = down[base+d] + down[base+2048+d] + down[base+4096+d] + down[base+6144+d];
    outf[(size_t)t*2048 + d] += s;
  }
}

// ---------------- shared-expert silu -> bf16 ----------------
__global__ __launch_bounds__(256) void silu_sh(const float* __restrict__ sgu,
                                               ushort* __restrict__ shact){
  int i = blockIdx.x*256 + threadIdx.x;
  if (i >= 2048*256) return;
  int row = i >> 8, jc = i & 255;
  float4 g4 = ((const float4*)(sgu + (size_t)row*2048))[jc];
  float4 u4 = ((const float4*)(sgu + (size_t)row*2048 + 1024))[jc];
  ushort4 o;
  o.x = f2bf(g4.x/(1.f+expf(-g4.x))*u4.x);
  o.y = f2bf(g4.y/(1.f+expf(-g4.y))*u4.y);
  o.z = f2bf(g4.z/(1.f+expf(-g4.z))*u4.z);
  o.w = f2bf(g4.w/(1.f+expf(-g4.w))*u4.w);
  ((ushort4*)(shact + (size_t)row*1024))[jc] = o;
}

// ---------------- host ----------------
static void launch_gemm(const float* A, int lda, const float* B, int ldb,
                        float* C, int ldc, const float* addsrc, int ldadd,
                        int M, int N, int K, float alpha, hipStream_t stream){
  if (N >= 256){
    dim3 grid((N+127)/128, (M+127)/128);
    gemm_f32_128<<<grid, 256, 0, stream>>>(A, lda, B, ldb, C, ldc, addsrc, ldadd, M, N, K, alpha);
  } else {
    dim3 grid((N+63)/64, (M+63)/64);
    gemm_f32<<<grid, 256, 0, stream>>>(A, lda, B, ldb, C, ldc, addsrc, ldadd, M, N, K, alpha);
  }
}

extern "C" void kernel_launch(void* const* d_in, const int* in_sizes, int n_in,
                              void* d_out, int out_size, void* d_ws, size_t ws_size,
                              hipStream_t stream){
  const int*   positions  = (const int*)  d_in[0];
  const float* hidden     = (const float*)d_in[1];
  const float* ln1_w      = (const float*)d_in[2];
  const float* ln2_w      = (const float*)d_in[3];
  const float* w_qkv_a    = (const float*)d_in[4];
  const float* q_a_ln_w   = (const float*)d_in[5];
  const float* kv_a_ln_w  = (const float*)d_in[6];
  const float* w_q_b      = (const float*)d_in[7];
  const float* w_kv_b     = (const float*)d_in[8];
  const float* w_o        = (const float*)d_in[9];
  const float* w_idx_k    = (const float*)d_in[10];
  const float* idx_k_ln_w = (const float*)d_in[11];
  const float* idx_k_ln_b = (const float*)d_in[12];
  const float* w_idx_qb   = (const float*)d_in[13];
  const float* w_idx_w    = (const float*)d_in[14];
  const float* w_gate     = (const float*)d_in[15];
  const float* w_moe_gu   = (const float*)d_in[16];
  const float* w_moe_d    = (const float*)d_in[17];
  const float* w_sh_gu    = (const float*)d_in[18];
  const float* w_sh_d     = (const float*)d_in[19];

  float* out_final = (float*)d_out;                       // [T,2048]
  float* residual  = (float*)d_out + (size_t)T_TOK*HIDN;  // [T,2048]

  float* ws = (float*)d_ws;
  // ---- arena (19,005,440 floats) with phase overlays ----
  float* arena   = ws;
  float* qkv     = arena;                  // [T,2112]  phase1
  float* iscores = arena;                  // [T,T]     overlays qkv (dead)
  float* qbuf    = arena + 4325376;        // [T,16,192]
  float* idx_q   = arena + 10616832;       // [T,16,128]
  float* q_c     = arena + 14811136;       // [T,1536]
  float* kv_c    = arena + 17956864;       // [T,512]
  float* sgu     = arena;                  // [T,2048]  phase2 (shared expert)
  float* gu_buf  = arena;                  // [8192,1024]
  float* down_buf= arena;                  // [8192,2048]
  ushort* act_bf = (ushort*)(arena + 16777216); // [8192,512] bf16
  // ---- fixed fp32 tail ----
  size_t off = 19005440;
  float* h      = ws + off; off += 4194304;   // [T,2048]
  float* kv     = ws + off; off += 8388608;   // [T,16,256] fp32 (later wmgu_t overlay)
  float* attnbuf= ws + off; off += 4194304;   // [T,2048] fp32 (later wmd_t overlay)
  float* k_pe   = ws + off; off += 131072;
  float* idx_k  = ws + off; off += 262144;
  float* idx_w  = ws + off; off += 32768;
  float* glog   = ws + off; off += 16384;
  float* tw     = ws + off; off += 8192;
  float* ctab   = ws + off; off += 65536;
  float* stab   = ws + off; off += 65536;
  int* list     = (int*)(ws + off);           // [T,512]
  int* cnt      = list + 1048576;
  int* ecnt     = cnt + 2048;
  int* elist    = ecnt + 8;
  off += 1067016;
  // ---- ushort region ----
  ushort* h2_bf   = (ushort*)(ws + off);      // [T,2048] bf16
  off += 2097152;
  ushort* shact_bf= (ushort*)(ws + off);      // [T,1024] bf16
  off += 1048576;
  ushort* wshgu_t = (ushort*)(ws + off);      // [2048,2048] bf16
  off += 2097152;
  ushort* wshd_t  = (ushort*)(ws + off);      // [2048,1024] bf16
  off += 1048576;                             // total 43,722,760 floats = 174.9 MB
  // MoE transposed weights overlay dead fp32 buffers (transposed after attn/w_o):
  ushort* wmgu_t = (ushort*)kv;               // [8,1024,2048] bf16 = 16,777,216 u
  ushort* wmd_t  = (ushort*)attnbuf;          // [8,2048,512]  bf16 =  8,388,608 u
  size_t total_bytes = off * sizeof(float);
  if (ws_size < total_bytes) return;

  // shared-expert weight transposes (consumed after gate)
  transconv<<<dim3(64,64,1), 256, 0, stream>>>(w_sh_gu, wshgu_t, 2048, 2048);
  transconv<<<dim3(64,32,1), 256, 0, stream>>>(w_sh_d,  wshd_t,  1024, 2048);

  rope_table_kernel<<<T_TOK, 32, 0, stream>>>(positions, ctab, stab);
  rmsnorm_kernel<<<T_TOK, 256, 0, stream>>>(hidden, HIDN, 0, ln1_w, h, HIDN, HIDN);
  launch_gemm(h, HIDN, w_qkv_a, 2112, qkv, 2112, nullptr, 0, T_TOK, 2112, HIDN, 1.f, stream);
  rmsnorm_kernel<<<T_TOK, 256, 0, stream>>>(qkv, 2112, 0,    q_a_ln_w,  q_c,  QLRr,  QLRr);
  rmsnorm_kernel<<<T_TOK, 256, 0, stream>>>(qkv, 2112, QLRr, kv_a_ln_w, kv_c, KVLRr, KVLRr);
  rope_kpe_kernel<<<T_TOK, 32, 0, stream>>>(qkv, ctab, stab, k_pe);
  launch_gemm(h, HIDN, w_idx_k, IHDd, idx_k, IHDd, nullptr, 0, T_TOK, IHDd, HIDN, 1.f, stream);
  ln_rope_idxk_kernel<<<T_TOK, 128, 0, stream>>>(idx_k, idx_k_ln_w, idx_k_ln_b, ctab, stab);
  launch_gemm(q_c, QLRr, w_q_b, NHEAD*QKDd, qbuf, NHEAD*QKDd, nullptr, 0, T_TOK, NHEAD*QKDd, QLRr, 1.f, stream);
  rope_q_kernel<<<T_TOK, 256, 0, stream>>>(qbuf, ctab, stab);
  launch_gemm(q_c, QLRr, w_idx_qb, INHh*IHDd, idx_q, INHh*IHDd, nullptr, 0, T_TOK, INHh*IHDd, QLRr, 1.f, stream);
  rope_idxq_kernel<<<T_TOK, 256, 0, stream>>>(idx_q, ctab, stab);
  launch_gemm(h, HIDN, w_idx_w, INHh, idx_w, INHh, nullptr, 0, T_TOK, INHh, HIDN, 0.02209708691207961f, stream);
  iscores_kernel<<<dim3(32,32), 256, 0, stream>>>(idx_q, idx_k, idx_w, iscores);
  topk_kernel<<<T_TOK, 256, 0, stream>>>(iscores, list, cnt);
  launch_gemm(kv_c, KVLRr, w_kv_b, NHEAD*(DNn+DVv), kv, NHEAD*(DNn+DVv), nullptr, 0, T_TOK, NHEAD*(DNn+DVv), KVLRr, 1.f, stream);
  attn_kernel<<<dim3(T_TOK, NHEAD/HG), 256, 0, stream>>>(qbuf, kv, k_pe, list, cnt, attnbuf);
  launch_gemm(attnbuf, NHEAD*DVv, w_o, HIDN, residual, HIDN, hidden, HIDN, T_TOK, HIDN, NHEAD*DVv, 1.f, stream);
  // kv/attnbuf now dead -> MoE weight transposes into their space
  transconv<<<dim3(32,64,8), 256, 0, stream>>>(w_moe_gu, wmgu_t, 2048, 1024);
  transconv<<<dim3(64,16,8), 256, 0, stream>>>(w_moe_d,  wmd_t,  512,  2048);
  rmsnorm_kernel<<<T_TOK, 256, 0, stream>>>(residual, HIDN, 0, ln2_w, h, HIDN, HIDN);
  launch_gemm(h, HIDN, w_gate, NEXP, glog, NEXP, nullptr, 0, T_TOK, NEXP, HIDN, 1.f, stream);
  hipMemsetAsync(ecnt, 0, NEXP*sizeof(int), stream);
  gate_kernel<<<8, 256, 0, stream>>>(glog, tw, ecnt, elist);
  conv_bf16<<<4096, 256, 0, stream>>>(h, h2_bf, 1048576);
  // shared expert first (arena as sgu)
  gemm_bf16s<0><<<dim3(16,16), 256, 0, stream>>>(h2_bf, wshgu_t, sgu, nullptr, nullptr, 2048, 2048);
  silu_sh<<<2048, 256, 0, stream>>>(sgu, shact_bf);
  gemm_bf16s<0><<<dim3(16,16), 256, 0, stream>>>(shact_bf, wshd_t, out_final, nullptr, nullptr, 2048, 1024);
  // MoE (arena as gu -> act_bf -> down)
  moe_gemm1s<<<dim3(8, 16, NEXP), 256, 0, stream>>>(h2_bf, wmgu_t, ecnt, elist, gu_buf);
  silu_moe<<<4096, 256, 0, stream>>>(gu_buf, act_bf);
  moe_gemm2s<<<dim3(16, 16, NEXP), 256, 0, stream>>>(act_bf, wmd_t, ecnt, elist, tw, down_buf);
  moe_combine<<<T_TOK, 256, 0, stream>>>(down_buf, out_final);
  (void)in_sizes; (void)n_in; (void)out_size;
}